// Round 4
// baseline (1204.623 us; speedup 1.0000x reference)
//
#include <hip/hip_runtime.h>
#include <hip/hip_bf16.h>
#include <math.h>

// Problem constants (fixed by reference)
#define B_ 2
#define S_ 2048
#define D_ 1024
#define M_ (B_*S_)      // 4096 rows

typedef _Float16 half8_t __attribute__((ext_vector_type(8)));
typedef _Float16 half4_t __attribute__((ext_vector_type(4)));
typedef float    f32x4  __attribute__((ext_vector_type(4)));

// async global->LDS, 16B per lane, wave-uniform LDS base + lane*16
#define GL2LDS(g, l) __builtin_amdgcn_global_load_lds( \
    (const __attribute__((address_space(1))) void*)(uintptr_t)(g), \
    (__attribute__((address_space(3))) void*)(l), 16, 0, 0)

// ---------------------------------------------------------------------------
// Batched fp16-MFMA GEMM: C = A @ W^T + bias. blockIdx.z selects batch ptrs.
// 128x128 tile, BK=32, 256 thr = 4 waves, each wave 64x64 via 4x4 of 16x16x32.
// MODE 0: C fp32. MODE 1: C fp16.
// MODE 2 (QKV split): cols <2048 -> fp16 C[row][col] (ldc=2048);
//                     cols>=2048 -> fp16 C2 = vT[col-2048][row] (transposed V).
// ---------------------------------------------------------------------------
struct GemmBatch {
    const _Float16* A;
    const _Float16* W;
    const float*    bias;
    void*           C;
    void*           C2;
};

template<int MODE>
__global__ __launch_bounds__(256) void gemm_f16(
    GemmBatch b0, GemmBatch b1, int lda, int ldw, int ldc, int K)
{
    __shared__ __align__(16) _Float16 As[128*32];
    __shared__ __align__(16) _Float16 Bs[128*32];

    const GemmBatch G = blockIdx.z ? b1 : b0;

    const int t    = threadIdx.x;
    const int lane = t & 63;
    const int w    = t >> 6;
    const int bm   = blockIdx.x * 128;
    const int bn   = blockIdx.y * 128;
    const int wm   = (w >> 1) * 64;
    const int wn   = (w & 1) * 64;

    f32x4 acc[4][4] = {};

    const int c0 = w * 2;
    const int g0 = c0 * 64 + lane;
    const int g1 = g0 + 64;
    const int r0 = g0 >> 2, k80 = (g0 & 3) * 8;
    const int r1 = g1 >> 2, k81 = (g1 & 3) * 8;

    const _Float16* a0 = G.A + (size_t)(bm + r0) * lda + k80;
    const _Float16* a1 = G.A + (size_t)(bm + r1) * lda + k81;
    const _Float16* w0 = G.W + (size_t)(bn + r0) * ldw + k80;
    const _Float16* w1 = G.W + (size_t)(bn + r1) * ldw + k81;

    const int fr = lane & 15;          // fragment row/col within 16x16
    const int q8 = (lane >> 4) * 8;    // k offset of this lane's 8 elems

    for (int k0 = 0; k0 < K; k0 += 32) {
        __syncthreads();
        GL2LDS(a0 + k0, As + c0*512);
        GL2LDS(a1 + k0, As + c0*512 + 512);
        GL2LDS(w0 + k0, Bs + c0*512);
        GL2LDS(w1 + k0, Bs + c0*512 + 512);
        __syncthreads();

        half8_t af[4], bf[4];
        #pragma unroll
        for (int mt = 0; mt < 4; mt++)
            af[mt] = *(const half8_t*)&As[(wm + mt*16 + fr)*32 + q8];
        #pragma unroll
        for (int nt = 0; nt < 4; nt++)
            bf[nt] = *(const half8_t*)&Bs[(wn + nt*16 + fr)*32 + q8];
        #pragma unroll
        for (int mt = 0; mt < 4; mt++)
            #pragma unroll
            for (int nt = 0; nt < 4; nt++)
                acc[mt][nt] = __builtin_amdgcn_mfma_f32_16x16x32_f16(
                    af[mt], bf[nt], acc[mt][nt], 0, 0, 0);
    }

    // C/D layout: col = lane&15, row = (lane>>4)*4 + reg
    const int cl = lane & 15;
    const int rq = (lane >> 4) * 4;

    if (MODE == 2 && bn >= 2048) {
        #pragma unroll
        for (int mt = 0; mt < 4; mt++) {
            int row0 = bm + wm + mt*16 + rq;
            #pragma unroll
            for (int nt = 0; nt < 4; nt++) {
                int gcol = bn + wn + nt*16 + cl;
                float bv = G.bias[gcol];
                half4_t hv = {(_Float16)(acc[mt][nt][0] + bv),
                              (_Float16)(acc[mt][nt][1] + bv),
                              (_Float16)(acc[mt][nt][2] + bv),
                              (_Float16)(acc[mt][nt][3] + bv)};
                *(half4_t*)((_Float16*)G.C2 + (size_t)(gcol - 2048) * M_ + row0) = hv;
            }
        }
        return;
    }

    #pragma unroll
    for (int mt = 0; mt < 4; mt++) {
        #pragma unroll
        for (int r = 0; r < 4; r++) {
            size_t grow = (size_t)(bm + wm + mt*16 + rq + r);
            #pragma unroll
            for (int nt = 0; nt < 4; nt++) {
                int gcol = bn + wn + nt*16 + cl;
                float v = acc[mt][nt][r] + G.bias[gcol];
                if (MODE == 0)
                    ((float*)G.C)[grow * ldc + gcol] = v;
                else
                    ((_Float16*)G.C)[grow * ldc + gcol] = (_Float16)v;
            }
        }
    }
}

// ---------------------------------------------------------------------------
// Fused fp32 -> fp16 cast for all 8 tensors in one dispatch.
// ---------------------------------------------------------------------------
struct CastArgs {
    const float* s[8];
    _Float16*    d[8];
    int          nb[8];   // blocks per segment (n4/256)
};

__global__ __launch_bounds__(256) void cast_all(CastArgs a)
{
    int off = blockIdx.x;
    int seg = 0;
    while (off >= a.nb[seg]) { off -= a.nb[seg]; seg++; }
    int i = off * 256 + threadIdx.x;
    float4 v = ((const float4*)a.s[seg])[i];
    half4_t h = {(_Float16)v.x, (_Float16)v.y, (_Float16)v.z, (_Float16)v.w};
    ((half4_t*)a.d[seg])[i] = h;
}

// ---------------------------------------------------------------------------
// Barrier-free MFMA flash attention.
// Every MFMA operand is a 16B-contiguous row slice -> direct global loads:
//   S^T = K Q^T   (A-frag = K rows, B-frag = Q rows)
//   PV            (A-frag = P rows from per-wave LDS patch, B-frag = vT rows)
// Each wave owns a 16-q strip and loops all j-tiles privately; the only LDS
// is the per-wave P transpose patch + l remap (in-wave ordered, no barrier).
// No max-subtraction: |s*scale| < ~3, exp2 exact in fp32 (softmax shift-inv).
// NBR=2 merges two branches (blockIdx.z = branch*2 + batch).
// ---------------------------------------------------------------------------
template<int DK, int H, int NBR, bool LOUT>
__global__ __launch_bounds__(256) void flash2(
    const _Float16* __restrict__ qk0, const _Float16* __restrict__ qk1,
    const _Float16* __restrict__ vT0, const _Float16* __restrict__ vT1,
    _Float16* __restrict__ ctx0, _Float16* __restrict__ ctx1,
    float* __restrict__ lout, int win0, int win1)
{
    constexpr int KS = DK / 32;    // score k-chunks
    constexpr int DT = DK / 16;    // PV d-tiles
    constexpr int LDP = 72;        // Ps row stride (halfs)

    __shared__ _Float16 Ps[4 * 16 * LDP];   // per-wave 16q x 64j patches
    __shared__ float    Lw[64];             // per-wave l remap

    const int t = threadIdx.x, lane = t & 63, w = t >> 6;
    const int fr = lane & 15, g = lane >> 4, k8 = g * 8;
    const int qlo = blockIdx.x * 64 + w * 16;   // wave's q strip
    const int h   = blockIdx.y;

    int br, b;
    if (NBR == 2) { br = blockIdx.z >> 1; b = blockIdx.z & 1; }
    else          { br = 0;               b = blockIdx.z;     }

    const _Float16* qk = br ? qk1 : qk0;
    const _Float16* vT = br ? vT1 : vT0;
    _Float16*      ctx = br ? ctx1 : ctx0;
    const int   window = br ? win1 : win0;

    // scale * log2(e) folded: p = exp2(s * sc)
    const float sc = ((DK == 128) ? 0.08838834764831845f : 0.125f) * 1.44269504f;

    _Float16* PsW = Ps + w * 16 * LDP;

    // Q fragments for this wave's strip, loaded once (B-operand: Q[q=fr][k])
    half8_t qf[KS];
    #pragma unroll
    for (int kk = 0; kk < KS; kk++)
        qf[kk] = *(const half8_t*)&qk[(size_t)(b*S_ + qlo + fr)*2048 + h*DK + kk*32 + k8];

    f32x4 O[DT] = {};
    float lsum = 0.f;

    for (int j0 = 0; j0 < S_; j0 += 64) {
        if (window >= 0 && j0 + 63 < qlo - window) continue;   // fully masked for strip

        // ---- scores S^T[j][q] over 4 j-subtiles ----
        f32x4 st[4];
        #pragma unroll
        for (int jt = 0; jt < 4; jt++) {
            f32x4 s = {};
            #pragma unroll
            for (int kk = 0; kk < KS; kk++) {
                half8_t kf = *(const half8_t*)
                    &qk[(size_t)(b*S_ + j0 + jt*16 + fr)*2048 + 1024 + h*DK + kk*32 + k8];
                s = __builtin_amdgcn_mfma_f32_16x16x32_f16(kf, qf[kk], s, 0, 0, 0);
            }
            st[jt] = s;
        }

        // ---- exp + mask; lane holds q=fr (col), j=jt*16+g*4+reg (rows) ----
        const bool full = (window < 0) || (j0 >= qlo + 15 - window);
        #pragma unroll
        for (int jt = 0; jt < 4; jt++) {
            float p[4];
            #pragma unroll
            for (int r = 0; r < 4; r++) {
                float pv = exp2f(st[jt][r] * sc);
                if (!full) {
                    int jg = j0 + jt*16 + g*4 + r;
                    if (jg < (qlo + fr) - window) pv = 0.f;
                }
                p[r] = pv;
                lsum += pv;
            }
            half4_t ph = {(_Float16)p[0], (_Float16)p[1],
                          (_Float16)p[2], (_Float16)p[3]};
            *(half4_t*)&PsW[fr*LDP + jt*16 + g*4] = ph;   // row-major-in-j
        }

        // ---- PV: O[q][d] += P[q][j] vT[d][j]  (in-wave LDS roundtrip) ----
        #pragma unroll
        for (int kc = 0; kc < 2; kc++) {
            half8_t pf = *(const half8_t*)&PsW[fr*LDP + kc*32 + k8];
            #pragma unroll
            for (int dt = 0; dt < DT; dt++) {
                half8_t vf = *(const half8_t*)
                    &vT[(size_t)(h*DK + dt*16 + fr)*M_ + b*S_ + j0 + kc*32 + k8];
                O[dt] = __builtin_amdgcn_mfma_f32_16x16x32_f16(pf, vf, O[dt], 0, 0, 0);
            }
        }
    }

    // ---- per-q row sums: reduce over g-groups, remap lanes via wave LDS ----
    lsum += __shfl_xor(lsum, 16);
    lsum += __shfl_xor(lsum, 32);
    if (g == 0) Lw[w*16 + fr] = lsum;          // q = fr
    float linv[4];
    #pragma unroll
    for (int r = 0; r < 4; r++)
        linv[r] = 1.f / Lw[w*16 + g*4 + r];    // q = g*4+r (in-wave order)

    if (LOUT && g == 0)
        lout[(size_t)(b*H + h)*S_ + qlo + fr] = lsum;

    // ---- epilogue: ctx = O / l  (O: row=g*4+reg=q, col=fr=d-sub) ----
    #pragma unroll
    for (int r = 0; r < 4; r++) {
        _Float16* cp = ctx + (size_t)(b*S_ + qlo + g*4 + r)*D_ + h*DK;
        #pragma unroll
        for (int dt = 0; dt < DT; dt++)
            cp[dt*16 + fr] = (_Float16)(O[dt][r] * linv[r]);
    }
}

// ---------------------------------------------------------------------------
// Head-averaged long-branch attention probabilities, barrier-free:
//   attn[b,i,j] = sum_h exp2(s_h*c1 - log2(l_h,i) - 4)
// Block = 64i x 128j; wave owns 16 i-rows; direct-global MFMA operands.
// ---------------------------------------------------------------------------
__global__ __launch_bounds__(256) void attn_mean2(
    const _Float16* __restrict__ qk,   // long-branch [M_][2048]
    const float* __restrict__ lbuf,    // [B_*16*S_]
    float* __restrict__ attn)          // [B_,S_,S_]
{
    const int t = threadIdx.x, lane = t & 63, w = t >> 6;
    const int fr = lane & 15, g = lane >> 4, k8 = g * 8;
    const int j0 = blockIdx.x * 128;
    const int irow = blockIdx.y * 64 + w * 16;
    const int b = blockIdx.z;
    const float c1 = 0.125f * 1.44269504f;

    f32x4 acc[8] = {};

    for (int h = 0; h < 16; h++) {
        half8_t af[2];
        #pragma unroll
        for (int kk = 0; kk < 2; kk++)
            af[kk] = *(const half8_t*)
                &qk[(size_t)(b*S_ + irow + fr)*2048 + h*64 + kk*32 + k8];

        float lg[4];
        #pragma unroll
        for (int r = 0; r < 4; r++)
            lg[r] = __log2f(lbuf[(size_t)(b*16 + h)*S_ + irow + g*4 + r]) + 4.0f;

        #pragma unroll
        for (int nt = 0; nt < 8; nt++) {
            f32x4 s = {};
            #pragma unroll
            for (int kk = 0; kk < 2; kk++) {
                half8_t bf = *(const half8_t*)
                    &qk[(size_t)(b*S_ + j0 + nt*16 + fr)*2048 + 1024 + h*64 + kk*32 + k8];
                s = __builtin_amdgcn_mfma_f32_16x16x32_f16(af[kk], bf, s, 0, 0, 0);
            }
            #pragma unroll
            for (int r = 0; r < 4; r++)
                acc[nt][r] += exp2f(s[r] * c1 - lg[r]);
        }
    }

    #pragma unroll
    for (int r = 0; r < 4; r++) {
        float* p = attn + (size_t)(b*S_ + irow + g*4 + r)*S_ + j0;
        #pragma unroll
        for (int nt = 0; nt < 8; nt++)
            p[nt*16 + fr] = acc[nt][r];
    }
}

// ---------------------------------------------------------------------------
// Residual + LayerNorm
// ---------------------------------------------------------------------------
__global__ __launch_bounds__(256) void ln_residual(
    const float* __restrict__ pre, const float* __restrict__ x,
    const float* __restrict__ gamma, const float* __restrict__ beta,
    float* __restrict__ out)
{
    __shared__ float redS[4], redQ[4];
    const int row = blockIdx.x;
    const int t = threadIdx.x;
    size_t base = (size_t)row * D_ + t * 4;

    float4 v  = *(const float4*)(pre + base);
    float4 xv = *(const float4*)(x + base);
    v.x += xv.x; v.y += xv.y; v.z += xv.z; v.w += xv.w;

    float s = v.x + v.y + v.z + v.w;
    float q = v.x*v.x + v.y*v.y + v.z*v.z + v.w*v.w;
    #pragma unroll
    for (int m = 32; m >= 1; m >>= 1) {
        s += __shfl_xor(s, m);
        q += __shfl_xor(q, m);
    }
    int wave = t >> 6;
    if ((t & 63) == 0) { redS[wave] = s; redQ[wave] = q; }
    __syncthreads();
    s = redS[0] + redS[1] + redS[2] + redS[3];
    q = redQ[0] + redQ[1] + redQ[2] + redQ[3];

    float mean = s * (1.f / D_);
    float var  = q * (1.f / D_) - mean * mean;
    float rstd = rsqrtf(var + 1e-5f);

    float4 g  = *(const float4*)(gamma + t * 4);
    float4 be = *(const float4*)(beta + t * 4);
    float4 o;
    o.x = (v.x - mean) * rstd * g.x + be.x;
    o.y = (v.y - mean) * rstd * g.y + be.y;
    o.z = (v.z - mean) * rstd * g.z + be.z;
    o.w = (v.w - mean) * rstd * g.w + be.w;
    *(float4*)(out + base) = o;
}

// ---------------------------------------------------------------------------
extern "C" void kernel_launch(void* const* d_in, const int* in_sizes, int n_in,
                              void* d_out, int out_size, void* d_ws, size_t ws_size,
                              hipStream_t stream)
{
    (void)in_sizes; (void)n_in; (void)out_size; (void)ws_size;
    const float* x      = (const float*)d_in[0];
    const float* w_in_s = (const float*)d_in[1];
    const float* b_in_s = (const float*)d_in[2];
    const float* wo_s   = (const float*)d_in[3];
    const float* bo_s   = (const float*)d_in[4];
    const float* w_in_m = (const float*)d_in[5];
    const float* b_in_m = (const float*)d_in[6];
    const float* wo_m   = (const float*)d_in[7];
    const float* bo_m   = (const float*)d_in[8];
    const float* w_in_l = (const float*)d_in[9];
    const float* b_in_l = (const float*)d_in[10];
    const float* wo_l   = (const float*)d_in[11];
    const float* bo_l   = (const float*)d_in[12];
    const float* w_comb = (const float*)d_in[13];
    const float* b_comb = (const float*)d_in[14];
    const float* gamma  = (const float*)d_in[15];
    const float* beta   = (const float*)d_in[16];

    float* out    = (float*)d_out;                 // [B,S,D]
    float* attn_o = out + (size_t)M_ * D_;         // [B,S,S]

    // Workspace layout (byte offsets; total 126.3 MB < proven-available 134.5 MB)
    char* W = (char*)d_ws;
    _Float16* qk_s   = (_Float16*)(W);               // 16MB  (reused: qk_l)
    _Float16* qk_m   = (_Float16*)(W + 16777216);    // 16MB  (reused: pre fp32)
    _Float16* vT_s   = (_Float16*)(W + 33554432);    //  8MB  (reused: vT_l)
    _Float16* vT_m   = (_Float16*)(W + 41943040);    //  8MB
    _Float16* ctx_s  = (_Float16*)(W + 50331648);    //  8MB  (reused: ctx_l)
    _Float16* ctx_m  = (_Float16*)(W + 58720256);    //  8MB
    _Float16* comb_h = (_Float16*)(W + 67108864);    // 24MB
    float*    lbuf   = (float*)   (W + 92274688);    // 256KB
    _Float16* x_h    = (_Float16*)(W + 92536832);    //  8MB
    _Float16* wpool  = (_Float16*)(W + 100925440);   // 30MB
    _Float16* qk_l   = qk_s;
    _Float16* vT_l   = vT_s;
    _Float16* ctx_l  = ctx_s;
    float*    pre    = (float*)qk_m;

    _Float16* w_in_s_h = wpool;
    _Float16* w_in_m_h = wpool + 3145728;
    _Float16* w_in_l_h = wpool + 6291456;
    _Float16* wo_s_h   = wpool + 9437184;
    _Float16* wo_m_h   = wpool + 10485760;
    _Float16* wo_l_h   = wpool + 11534336;
    _Float16* w_comb_h = wpool + 12582912;

    dim3 blk(256);

    // ---- fused casts (fp32 -> fp16), one dispatch ----
    CastArgs ca;
    ca.s[0]=x;      ca.d[0]=x_h;      ca.nb[0]=4096;
    ca.s[1]=w_in_s; ca.d[1]=w_in_s_h; ca.nb[1]=3072;
    ca.s[2]=w_in_m; ca.d[2]=w_in_m_h; ca.nb[2]=3072;
    ca.s[3]=w_in_l; ca.d[3]=w_in_l_h; ca.nb[3]=3072;
    ca.s[4]=wo_s;   ca.d[4]=wo_s_h;   ca.nb[4]=1024;
    ca.s[5]=wo_m;   ca.d[5]=wo_m_h;   ca.nb[5]=1024;
    ca.s[6]=wo_l;   ca.d[6]=wo_l_h;   ca.nb[6]=1024;
    ca.s[7]=w_comb; ca.d[7]=w_comb_h; ca.nb[7]=3072;
    cast_all<<<dim3(19456), blk, 0, stream>>>(ca);

    // ---- QKV projections, short+medium in one dispatch ----
    GemmBatch qs = { x_h, w_in_s_h, b_in_s, qk_s, vT_s };
    GemmBatch qm = { x_h, w_in_m_h, b_in_m, qk_m, vT_m };
    gemm_f16<2><<<dim3(M_/128, 3072/128, 2), blk, 0, stream>>>(qs, qm, D_, D_, 2048, D_);

    // ---- short+medium flash, one dispatch (z = branch*2 + batch) ----
    flash2<128, 8, 2, false><<<dim3(S_/64, 8, 4), blk, 0, stream>>>(
        qk_s, qk_m, vT_s, vT_m, ctx_s, ctx_m, nullptr, 10, 30);

    // ---- short+medium out-proj, one dispatch ----
    GemmBatch ps = { ctx_s, wo_s_h, bo_s, comb_h + 0,    nullptr };
    GemmBatch pm = { ctx_m, wo_m_h, bo_m, comb_h + 1024, nullptr };
    gemm_f16<1><<<dim3(M_/128, D_/128, 2), blk, 0, stream>>>(ps, pm, D_, D_, 3072, D_);

    // ---- long branch (qk_l/vT_l/ctx_l alias dead s-buffers) ----
    GemmBatch ql = { x_h, w_in_l_h, b_in_l, qk_l, vT_l };
    gemm_f16<2><<<dim3(M_/128, 3072/128, 1), blk, 0, stream>>>(ql, ql, D_, D_, 2048, D_);
    flash2<64, 16, 1, true><<<dim3(S_/64, 16, 2), blk, 0, stream>>>(
        qk_l, qk_l, vT_l, vT_l, ctx_l, ctx_l, lbuf, -1, -1);
    GemmBatch pl = { ctx_l, wo_l_h, bo_l, comb_h + 2048, nullptr };
    gemm_f16<1><<<dim3(M_/128, D_/128, 1), blk, 0, stream>>>(pl, pl, D_, D_, 3072, D_);

    // ---- head-averaged probabilities ----
    attn_mean2<<<dim3(S_/128, S_/64, B_), blk, 0, stream>>>(qk_l, lbuf, attn_o);

    // ---- combine + residual LayerNorm (pre aliases qk_m, dead) ----
    GemmBatch cb = { comb_h, w_comb_h, b_comb, pre, nullptr };
    gemm_f16<0><<<dim3(M_/128, D_/128, 1), blk, 0, stream>>>(cb, cb, 3072, 3072, D_, 3072);
    ln_residual<<<dim3(M_), blk, 0, stream>>>(pre, x, gamma, beta, out);
}

// Round 6
// 691.549 us; speedup vs baseline: 1.7419x; 1.7419x over previous
//
#include <hip/hip_runtime.h>
#include <hip/hip_bf16.h>
#include <math.h>

// Problem constants (fixed by reference)
#define B_ 2
#define S_ 2048
#define D_ 1024
#define M_ (B_*S_)      // 4096 rows

typedef _Float16 half8_t __attribute__((ext_vector_type(8)));
typedef _Float16 half4_t __attribute__((ext_vector_type(4)));
typedef float    f32x4  __attribute__((ext_vector_type(4)));

// async global->LDS: per-lane global addr; HW scatters lane i to (uniform LDS base) + i*16B
#define GL2LDS(g, l) __builtin_amdgcn_global_load_lds( \
    (const __attribute__((address_space(1))) void*)(uintptr_t)(g), \
    (__attribute__((address_space(3))) void*)(l), 16, 0, 0)

// ---------------------------------------------------------------------------
// Batched fp16-MFMA GEMM (m97 structure): C = A @ W^T + bias.
// 128x128 tile, BK=32, 4 waves, each wave 64x64 via 4x4 of 16x16x32.
// MODE 0: C fp32. MODE 1: C fp16. MODE 2: QKV split (V transposed to C2).
// ---------------------------------------------------------------------------
struct GemmBatch {
    const _Float16* A;
    const _Float16* W;
    const float*    bias;
    void*           C;
    void*           C2;
};

template<int MODE>
__global__ __launch_bounds__(256) void gemm_f16(
    GemmBatch b0, GemmBatch b1, int lda, int ldw, int ldc, int K)
{
    __shared__ __align__(16) _Float16 As[128*32];
    __shared__ __align__(16) _Float16 Bs[128*32];

    const GemmBatch G = blockIdx.z ? b1 : b0;

    const int t    = threadIdx.x;
    const int lane = t & 63;
    const int w    = t >> 6;
    const int bm   = blockIdx.x * 128;
    const int bn   = blockIdx.y * 128;
    const int wm   = (w >> 1) * 64;
    const int wn   = (w & 1) * 64;

    f32x4 acc[4][4] = {};

    const int c0 = w * 2;
    const int g0 = c0 * 64 + lane;
    const int g1 = g0 + 64;
    const int r0 = g0 >> 2, k80 = (g0 & 3) * 8;
    const int r1 = g1 >> 2, k81 = (g1 & 3) * 8;

    const _Float16* a0 = G.A + (size_t)(bm + r0) * lda + k80;
    const _Float16* a1 = G.A + (size_t)(bm + r1) * lda + k81;
    const _Float16* w0 = G.W + (size_t)(bn + r0) * ldw + k80;
    const _Float16* w1 = G.W + (size_t)(bn + r1) * ldw + k81;

    const int fr = lane & 15;
    const int q8 = (lane >> 4) * 8;

    for (int k0 = 0; k0 < K; k0 += 32) {
        __syncthreads();
        GL2LDS(a0 + k0, As + c0*512);
        GL2LDS(a1 + k0, As + c0*512 + 512);
        GL2LDS(w0 + k0, Bs + c0*512);
        GL2LDS(w1 + k0, Bs + c0*512 + 512);
        __syncthreads();

        half8_t af[4], bf[4];
        #pragma unroll
        for (int mt = 0; mt < 4; mt++)
            af[mt] = *(const half8_t*)&As[(wm + mt*16 + fr)*32 + q8];
        #pragma unroll
        for (int nt = 0; nt < 4; nt++)
            bf[nt] = *(const half8_t*)&Bs[(wn + nt*16 + fr)*32 + q8];
        #pragma unroll
        for (int mt = 0; mt < 4; mt++)
            #pragma unroll
            for (int nt = 0; nt < 4; nt++)
                acc[mt][nt] = __builtin_amdgcn_mfma_f32_16x16x32_f16(
                    af[mt], bf[nt], acc[mt][nt], 0, 0, 0);
    }

    const int cl = lane & 15;
    const int rq = (lane >> 4) * 4;

    if (MODE == 2 && bn >= 2048) {
        #pragma unroll
        for (int mt = 0; mt < 4; mt++) {
            int row0 = bm + wm + mt*16 + rq;
            #pragma unroll
            for (int nt = 0; nt < 4; nt++) {
                int gcol = bn + wn + nt*16 + cl;
                float bv = G.bias[gcol];
                half4_t hv = {(_Float16)(acc[mt][nt][0] + bv),
                              (_Float16)(acc[mt][nt][1] + bv),
                              (_Float16)(acc[mt][nt][2] + bv),
                              (_Float16)(acc[mt][nt][3] + bv)};
                *(half4_t*)((_Float16*)G.C2 + (size_t)(gcol - 2048) * M_ + row0) = hv;
            }
        }
        return;
    }

    #pragma unroll
    for (int mt = 0; mt < 4; mt++) {
        #pragma unroll
        for (int r = 0; r < 4; r++) {
            size_t grow = (size_t)(bm + wm + mt*16 + rq + r);
            #pragma unroll
            for (int nt = 0; nt < 4; nt++) {
                int gcol = bn + wn + nt*16 + cl;
                float v = acc[mt][nt][r] + G.bias[gcol];
                if (MODE == 0)
                    ((float*)G.C)[grow * ldc + gcol] = v;
                else
                    ((_Float16*)G.C)[grow * ldc + gcol] = (_Float16)v;
            }
        }
    }
}

// ---------------------------------------------------------------------------
// Fused fp32 -> fp16 cast for all 8 tensors in one dispatch.
// ---------------------------------------------------------------------------
struct CastArgs {
    const float* s[8];
    _Float16*    d[8];
    int          nb[8];
};

__global__ __launch_bounds__(256) void cast_all(CastArgs a)
{
    int off = blockIdx.x;
    int seg = 0;
    while (off >= a.nb[seg]) { off -= a.nb[seg]; seg++; }
    int i = off * 256 + threadIdx.x;
    float4 v = ((const float4*)a.s[seg])[i];
    half4_t h = {(_Float16)v.x, (_Float16)v.y, (_Float16)v.z, (_Float16)v.w};
    ((half4_t*)a.d[seg])[i] = h;
}

// ---------------------------------------------------------------------------
// MFMA flash attention, LDS-staged K/V (chunk-major m97 layout, GL2LDS),
// per-wave q-strips (P stays in-wave -> only 2 barriers per j-tile).
//   S^T = K Q^T : A-frag = K rows (LDS), B-frag = Q rows (regs, loaded once)
//   PV          : A-frag = P (per-wave LDS patch), B-frag = vT rows (LDS)
// No max-subtraction: |s*scale| < ~3, exp2 exact in fp32 (softmax shift-inv).
// NBR=2 merges two branches (blockIdx.z = branch*2 + batch).
// LDP=72: 64 j-values per row + 8 pad (16B-aligned rows, 2-way-free banks).
// ---------------------------------------------------------------------------
template<int DK, int H, int NBR, bool LOUT>
__global__ __launch_bounds__(256) void flash3(
    const _Float16* __restrict__ qk0, const _Float16* __restrict__ qk1,
    const _Float16* __restrict__ vT0, const _Float16* __restrict__ vT1,
    _Float16* __restrict__ ctx0, _Float16* __restrict__ ctx1,
    float* __restrict__ lout, int win0, int win1)
{
    constexpr int KS  = DK / 32;     // K chunks (k-dim)
    constexpr int DT  = DK / 16;     // PV d-tiles
    constexpr int LDP = 72;          // Ps row stride (halfs) >= 64 + pad

    // chunk-major: [chunk][row][32 halfs] -> 64B row stride (m97 pattern)
    __shared__ __align__(16) _Float16 Ks[KS * 64 * 32];  // K tile:  64 j x DK
    __shared__ __align__(16) _Float16 Vs[2 * DK * 32];   // vT tile: DK d x 64 j
    __shared__ __align__(16) _Float16 Ps[4 * 16 * LDP];  // per-wave P patches
    __shared__ float Lw[64];

    const int t = threadIdx.x, lane = t & 63, w = t >> 6;
    const int fr = lane & 15, g = lane >> 4, k8 = g * 8;
    const int blkQ = blockIdx.x * 64;
    const int qlo  = blkQ + w * 16;             // wave's q strip
    const int h    = blockIdx.y;

    int br, b;
    if (NBR == 2) { br = blockIdx.z >> 1; b = blockIdx.z & 1; }
    else          { br = 0;               b = blockIdx.z;     }

    const _Float16* qk = br ? qk1 : qk0;
    const _Float16* vT = br ? vT1 : vT0;
    _Float16*      ctx = br ? ctx1 : ctx0;
    const int   window = br ? win1 : win0;

    const float sc = ((DK == 128) ? 0.08838834764831845f : 0.125f) * 1.44269504f;

    _Float16* PsW = Ps + w * 16 * LDP;

    // staging lane geometry: lane l -> row l>>2, halfs (l&3)*8 (HW: base + l*16B)
    const int srow = lane >> 2;
    const int scol = (lane & 3) * 8;

    // Q fragments for this wave's strip (loaded once)
    half8_t qf[KS];
    #pragma unroll
    for (int kk = 0; kk < KS; kk++)
        qf[kk] = *(const half8_t*)&qk[(size_t)(b*S_ + qlo + fr)*2048 + h*DK + kk*32 + k8];

    f32x4 O[DT] = {};
    float lsum = 0.f;

    for (int j0 = 0; j0 < S_; j0 += 64) {
        if (window >= 0 && j0 + 63 < blkQ - window) continue;  // block-uniform skip
        __syncthreads();   // prev tile's LDS reads done

        // ---- stage K: wave w covers rows w*16..+15 of each chunk ----
        #pragma unroll
        for (int kk = 0; kk < KS; kk++)
            GL2LDS(&qk[(size_t)(b*S_ + j0 + w*16 + srow)*2048 + 1024 + h*DK + kk*32 + scol],
                   &Ks[kk*2048 + w*512]);
        // ---- stage vT: wave w covers d-rows w*(DK/4).. of each j-chunk ----
        #pragma unroll
        for (int jc = 0; jc < 2; jc++)
            #pragma unroll
            for (int ii = 0; ii < DK/64; ii++)
                GL2LDS(&vT[(size_t)(h*DK + w*(DK/4) + ii*16 + srow)*M_
                           + b*S_ + j0 + jc*32 + scol],
                       &Vs[jc*DK*32 + w*(DK/4)*32 + ii*512]);
        __syncthreads();   // staging visible

        // ---- scores S^T[j][q] over 4 j-subtiles ----
        f32x4 st[4];
        #pragma unroll
        for (int jt = 0; jt < 4; jt++) {
            f32x4 s = {};
            #pragma unroll
            for (int kk = 0; kk < KS; kk++) {
                half8_t kf = *(const half8_t*)&Ks[kk*2048 + (jt*16 + fr)*32 + k8];
                s = __builtin_amdgcn_mfma_f32_16x16x32_f16(kf, qf[kk], s, 0, 0, 0);
            }
            st[jt] = s;
        }

        // ---- exp + mask; lane: q=fr (col), j=jt*16+g*4+reg (rows) ----
        const bool full = (window < 0) || (j0 >= qlo + 15 - window);
        #pragma unroll
        for (int jt = 0; jt < 4; jt++) {
            float p[4];
            #pragma unroll
            for (int r = 0; r < 4; r++) {
                float pv = exp2f(st[jt][r] * sc);
                if (!full) {
                    int jg = j0 + jt*16 + g*4 + r;
                    if (jg < (qlo + fr) - window) pv = 0.f;
                }
                p[r] = pv;
                lsum += pv;
            }
            half4_t ph = {(_Float16)p[0], (_Float16)p[1],
                          (_Float16)p[2], (_Float16)p[3]};
            *(half4_t*)&PsW[fr*LDP + jt*16 + g*4] = ph;
        }

        // ---- PV: O[q][d] += P[q][j] vT[d][j] (P in-wave, no barrier) ----
        #pragma unroll
        for (int kc = 0; kc < 2; kc++) {
            half8_t pf = *(const half8_t*)&PsW[fr*LDP + kc*32 + k8];
            #pragma unroll
            for (int dt = 0; dt < DT; dt++) {
                half8_t vf = *(const half8_t*)&Vs[kc*DK*32 + (dt*16 + fr)*32 + k8];
                O[dt] = __builtin_amdgcn_mfma_f32_16x16x32_f16(pf, vf, O[dt], 0, 0, 0);
            }
        }
    }

    // ---- per-q row sums (reduce g-groups, remap lanes via wave-local LDS) ----
    lsum += __shfl_xor(lsum, 16);
    lsum += __shfl_xor(lsum, 32);
    if (g == 0) Lw[w*16 + fr] = lsum;
    float linv[4];
    #pragma unroll
    for (int r = 0; r < 4; r++)
        linv[r] = 1.f / Lw[w*16 + g*4 + r];

    if (LOUT && g == 0)
        lout[(size_t)(b*H + h)*S_ + qlo + fr] = lsum;

    // ---- epilogue: ctx = O / l (O row=g*4+reg=q, col=fr=d-sub) ----
    #pragma unroll
    for (int r = 0; r < 4; r++) {
        _Float16* cp = ctx + (size_t)(b*S_ + qlo + g*4 + r)*D_ + h*DK;
        #pragma unroll
        for (int dt = 0; dt < DT; dt++)
            cp[dt*16 + fr] = (_Float16)(O[dt][r] * linv[r]);
    }
}

// ---------------------------------------------------------------------------
// Head-averaged long-branch attention probabilities, K LDS-staged per head:
//   attn[b,i,j] = sum_h exp2(s_h*c1 - log2(l_h,i) - 4)
// Block = 64i x 128j; wave owns 16 i-rows; Q frags direct (once per head).
// ---------------------------------------------------------------------------
__global__ __launch_bounds__(256) void attn_mean3(
    const _Float16* __restrict__ qk,   // long-branch [M_][2048]
    const float* __restrict__ lbuf,    // [B_*16*S_]
    float* __restrict__ attn)          // [B_,S_,S_]
{
    __shared__ __align__(16) _Float16 Ks[2 * 128 * 32];  // [chunk][jrow][32]

    const int t = threadIdx.x, lane = t & 63, w = t >> 6;
    const int fr = lane & 15, g = lane >> 4, k8 = g * 8;
    const int j0 = blockIdx.x * 128;
    const int irow = blockIdx.y * 64 + w * 16;
    const int b = blockIdx.z;
    const float c1 = 0.125f * 1.44269504f;
    const int srow = lane >> 2, scol = (lane & 3) * 8;

    f32x4 acc[8] = {};

    for (int h = 0; h < 16; h++) {
        __syncthreads();   // prev head's reads done
        // stage K: 128 j-rows x 2 chunks; wave w rows w*32..+31 per chunk
        #pragma unroll
        for (int kk = 0; kk < 2; kk++)
            #pragma unroll
            for (int ii = 0; ii < 2; ii++)
                GL2LDS(&qk[(size_t)(b*S_ + j0 + w*32 + ii*16 + srow)*2048
                           + 1024 + h*64 + kk*32 + scol],
                       &Ks[kk*4096 + w*1024 + ii*512]);
        __syncthreads();

        half8_t af[2];
        #pragma unroll
        for (int kk = 0; kk < 2; kk++)
            af[kk] = *(const half8_t*)
                &qk[(size_t)(b*S_ + irow + fr)*2048 + h*64 + kk*32 + k8];

        float lg[4];
        #pragma unroll
        for (int r = 0; r < 4; r++)
            lg[r] = __log2f(lbuf[(size_t)(b*16 + h)*S_ + irow + g*4 + r]) + 4.0f;

        #pragma unroll
        for (int nt = 0; nt < 8; nt++) {
            f32x4 s = {};
            #pragma unroll
            for (int kk = 0; kk < 2; kk++) {
                half8_t bf = *(const half8_t*)&Ks[kk*4096 + (nt*16 + fr)*32 + k8];
                s = __builtin_amdgcn_mfma_f32_16x16x32_f16(af[kk], bf, s, 0, 0, 0);
            }
            #pragma unroll
            for (int r = 0; r < 4; r++)
                acc[nt][r] += exp2f(s[r] * c1 - lg[r]);
        }
    }

    #pragma unroll
    for (int r = 0; r < 4; r++) {
        float* p = attn + (size_t)(b*S_ + irow + g*4 + r)*S_ + j0;
        #pragma unroll
        for (int nt = 0; nt < 8; nt++)
            p[nt*16 + fr] = acc[nt][r];
    }
}

// ---------------------------------------------------------------------------
// Residual + LayerNorm
// ---------------------------------------------------------------------------
__global__ __launch_bounds__(256) void ln_residual(
    const float* __restrict__ pre, const float* __restrict__ x,
    const float* __restrict__ gamma, const float* __restrict__ beta,
    float* __restrict__ out)
{
    __shared__ float redS[4], redQ[4];
    const int row = blockIdx.x;
    const int t = threadIdx.x;
    size_t base = (size_t)row * D_ + t * 4;

    float4 v  = *(const float4*)(pre + base);
    float4 xv = *(const float4*)(x + base);
    v.x += xv.x; v.y += xv.y; v.z += xv.z; v.w += xv.w;

    float s = v.x + v.y + v.z + v.w;
    float q = v.x*v.x + v.y*v.y + v.z*v.z + v.w*v.w;
    #pragma unroll
    for (int m = 32; m >= 1; m >>= 1) {
        s += __shfl_xor(s, m);
        q += __shfl_xor(q, m);
    }
    int wave = t >> 6;
    if ((t & 63) == 0) { redS[wave] = s; redQ[wave] = q; }
    __syncthreads();
    s = redS[0] + redS[1] + redS[2] + redS[3];
    q = redQ[0] + redQ[1] + redQ[2] + redQ[3];

    float mean = s * (1.f / D_);
    float var  = q * (1.f / D_) - mean * mean;
    float rstd = rsqrtf(var + 1e-5f);

    float4 g  = *(const float4*)(gamma + t * 4);
    float4 be = *(const float4*)(beta + t * 4);
    float4 o;
    o.x = (v.x - mean) * rstd * g.x + be.x;
    o.y = (v.y - mean) * rstd * g.y + be.y;
    o.z = (v.z - mean) * rstd * g.z + be.z;
    o.w = (v.w - mean) * rstd * g.w + be.w;
    *(float4*)(out + base) = o;
}

// ---------------------------------------------------------------------------
extern "C" void kernel_launch(void* const* d_in, const int* in_sizes, int n_in,
                              void* d_out, int out_size, void* d_ws, size_t ws_size,
                              hipStream_t stream)
{
    (void)in_sizes; (void)n_in; (void)out_size; (void)ws_size;
    const float* x      = (const float*)d_in[0];
    const float* w_in_s = (const float*)d_in[1];
    const float* b_in_s = (const float*)d_in[2];
    const float* wo_s   = (const float*)d_in[3];
    const float* bo_s   = (const float*)d_in[4];
    const float* w_in_m = (const float*)d_in[5];
    const float* b_in_m = (const float*)d_in[6];
    const float* wo_m   = (const float*)d_in[7];
    const float* bo_m   = (const float*)d_in[8];
    const float* w_in_l = (const float*)d_in[9];
    const float* b_in_l = (const float*)d_in[10];
    const float* wo_l   = (const float*)d_in[11];
    const float* bo_l   = (const float*)d_in[12];
    const float* w_comb = (const float*)d_in[13];
    const float* b_comb = (const float*)d_in[14];
    const float* gamma  = (const float*)d_in[15];
    const float* beta   = (const float*)d_in[16];

    float* out    = (float*)d_out;                 // [B,S,D]
    float* attn_o = out + (size_t)M_ * D_;         // [B,S,S]

    // Workspace layout (byte offsets; total ~126 MB)
    char* W = (char*)d_ws;
    _Float16* qk_s   = (_Float16*)(W);               // 16MB  (reused: qk_l)
    _Float16* qk_m   = (_Float16*)(W + 16777216);    // 16MB  (reused: pre fp32)
    _Float16* vT_s   = (_Float16*)(W + 33554432);    //  8MB  (reused: vT_l)
    _Float16* vT_m   = (_Float16*)(W + 41943040);    //  8MB
    _Float16* ctx_s  = (_Float16*)(W + 50331648);    //  8MB  (reused: ctx_l)
    _Float16* ctx_m  = (_Float16*)(W + 58720256);    //  8MB
    _Float16* comb_h = (_Float16*)(W + 67108864);    // 24MB
    float*    lbuf   = (float*)   (W + 92274688);    // 256KB
    _Float16* x_h    = (_Float16*)(W + 92536832);    //  8MB
    _Float16* wpool  = (_Float16*)(W + 100925440);   // 30MB
    _Float16* qk_l   = qk_s;
    _Float16* vT_l   = vT_s;
    _Float16* ctx_l  = ctx_s;
    float*    pre    = (float*)qk_m;

    _Float16* w_in_s_h = wpool;
    _Float16* w_in_m_h = wpool + 3145728;
    _Float16* w_in_l_h = wpool + 6291456;
    _Float16* wo_s_h   = wpool + 9437184;
    _Float16* wo_m_h   = wpool + 10485760;
    _Float16* wo_l_h   = wpool + 11534336;
    _Float16* w_comb_h = wpool + 12582912;

    dim3 blk(256);

    // ---- fused casts (fp32 -> fp16) ----
    CastArgs ca;
    ca.s[0]=x;      ca.d[0]=x_h;      ca.nb[0]=4096;
    ca.s[1]=w_in_s; ca.d[1]=w_in_s_h; ca.nb[1]=3072;
    ca.s[2]=w_in_m; ca.d[2]=w_in_m_h; ca.nb[2]=3072;
    ca.s[3]=w_in_l; ca.d[3]=w_in_l_h; ca.nb[3]=3072;
    ca.s[4]=wo_s;   ca.d[4]=wo_s_h;   ca.nb[4]=1024;
    ca.s[5]=wo_m;   ca.d[5]=wo_m_h;   ca.nb[5]=1024;
    ca.s[6]=wo_l;   ca.d[6]=wo_l_h;   ca.nb[6]=1024;
    ca.s[7]=w_comb; ca.d[7]=w_comb_h; ca.nb[7]=3072;
    cast_all<<<dim3(19456), blk, 0, stream>>>(ca);

    // ---- QKV projections, short+medium in one dispatch ----
    GemmBatch qs = { x_h, w_in_s_h, b_in_s, qk_s, vT_s };
    GemmBatch qm = { x_h, w_in_m_h, b_in_m, qk_m, vT_m };
    gemm_f16<2><<<dim3(M_/128, 3072/128, 2), blk, 0, stream>>>(qs, qm, D_, D_, 2048, D_);

    // ---- short+medium flash, one dispatch (z = branch*2 + batch) ----
    flash3<128, 8, 2, false><<<dim3(S_/64, 8, 4), blk, 0, stream>>>(
        qk_s, qk_m, vT_s, vT_m, ctx_s, ctx_m, nullptr, 10, 30);

    // ---- short+medium out-proj, one dispatch ----
    GemmBatch ps = { ctx_s, wo_s_h, bo_s, comb_h + 0,    nullptr };
    GemmBatch pm = { ctx_m, wo_m_h, bo_m, comb_h + 1024, nullptr };
    gemm_f16<1><<<dim3(M_/128, D_/128, 2), blk, 0, stream>>>(ps, pm, D_, D_, 3072, D_);

    // ---- long branch (aliases dead short-branch buffers) ----
    GemmBatch ql = { x_h, w_in_l_h, b_in_l, qk_l, vT_l };
    gemm_f16<2><<<dim3(M_/128, 3072/128, 1), blk, 0, stream>>>(ql, ql, D_, D_, 2048, D_);
    flash3<64, 16, 1, true><<<dim3(S_/64, 16, 2), blk, 0, stream>>>(
        qk_l, qk_l, vT_l, vT_l, ctx_l, ctx_l, lbuf, -1, -1);
    GemmBatch pl = { ctx_l, wo_l_h, bo_l, comb_h + 2048, nullptr };
    gemm_f16<1><<<dim3(M_/128, D_/128, 1), blk, 0, stream>>>(pl, pl, D_, D_, 3072, D_);

    // ---- head-averaged probabilities ----
    attn_mean3<<<dim3(S_/128, S_/64, B_), blk, 0, stream>>>(qk_l, lbuf, attn_o);

    // ---- combine + residual LayerNorm (pre aliases qk_m, dead) ----
    GemmBatch cb = { comb_h, w_comb_h, b_comb, pre, nullptr };
    gemm_f16<0><<<dim3(M_/128, D_/128, 1), blk, 0, stream>>>(cb, cb, 3072, 3072, D_, 3072);
    ln_residual<<<dim3(M_), blk, 0, stream>>>(pre, x, gamma, beta, out);
}

// Round 8
// 665.123 us; speedup vs baseline: 1.8111x; 1.0397x over previous
//
#include <hip/hip_runtime.h>
#include <hip/hip_bf16.h>
#include <math.h>

// Problem constants (fixed by reference)
#define B_ 2
#define S_ 2048
#define D_ 1024
#define M_ (B_*S_)      // 4096 rows

typedef _Float16 half8_t __attribute__((ext_vector_type(8)));
typedef _Float16 half4_t __attribute__((ext_vector_type(4)));
typedef float    f32x4  __attribute__((ext_vector_type(4)));

// async global->LDS: per-lane global addr; HW scatters lane i to (uniform LDS base) + i*16B
#define GL2LDS(g, l) __builtin_amdgcn_global_load_lds( \
    (const __attribute__((address_space(1))) void*)(uintptr_t)(g), \
    (__attribute__((address_space(3))) void*)(l), 16, 0, 0)

// ---------------------------------------------------------------------------
// Batched fp16-MFMA GEMM (m97 structure): C = A @ W^T + bias.
// 128x128 tile, BK=32, 4 waves, each wave 64x64 via 4x4 of 16x16x32.
// blockIdx.z selects batch {b0,b1,b2}.
// MODE 0: C fp32. MODE 1: C fp16. MODE 2: QKV split (V transposed to C2).
// ---------------------------------------------------------------------------
struct GemmBatch {
    const _Float16* A;
    const _Float16* W;
    const float*    bias;
    void*           C;
    void*           C2;
};

template<int MODE>
__global__ __launch_bounds__(256) void gemm_f16(
    GemmBatch b0, GemmBatch b1, GemmBatch b2, int lda, int ldw, int ldc, int K)
{
    __shared__ __align__(16) _Float16 As[128*32];
    __shared__ __align__(16) _Float16 Bs[128*32];

    const GemmBatch G = (blockIdx.z == 0) ? b0 : ((blockIdx.z == 1) ? b1 : b2);

    const int t    = threadIdx.x;
    const int lane = t & 63;
    const int w    = t >> 6;
    const int bm   = blockIdx.x * 128;
    const int bn   = blockIdx.y * 128;
    const int wm   = (w >> 1) * 64;
    const int wn   = (w & 1) * 64;

    f32x4 acc[4][4] = {};

    const int c0 = w * 2;
    const int g0 = c0 * 64 + lane;
    const int g1 = g0 + 64;
    const int r0 = g0 >> 2, k80 = (g0 & 3) * 8;
    const int r1 = g1 >> 2, k81 = (g1 & 3) * 8;

    const _Float16* a0 = G.A + (size_t)(bm + r0) * lda + k80;
    const _Float16* a1 = G.A + (size_t)(bm + r1) * lda + k81;
    const _Float16* w0 = G.W + (size_t)(bn + r0) * ldw + k80;
    const _Float16* w1 = G.W + (size_t)(bn + r1) * ldw + k81;

    const int fr = lane & 15;
    const int q8 = (lane >> 4) * 8;

    for (int k0 = 0; k0 < K; k0 += 32) {
        __syncthreads();
        GL2LDS(a0 + k0, As + c0*512);
        GL2LDS(a1 + k0, As + c0*512 + 512);
        GL2LDS(w0 + k0, Bs + c0*512);
        GL2LDS(w1 + k0, Bs + c0*512 + 512);
        __syncthreads();

        half8_t af[4], bf[4];
        #pragma unroll
        for (int mt = 0; mt < 4; mt++)
            af[mt] = *(const half8_t*)&As[(wm + mt*16 + fr)*32 + q8];
        #pragma unroll
        for (int nt = 0; nt < 4; nt++)
            bf[nt] = *(const half8_t*)&Bs[(wn + nt*16 + fr)*32 + q8];
        #pragma unroll
        for (int mt = 0; mt < 4; mt++)
            #pragma unroll
            for (int nt = 0; nt < 4; nt++)
                acc[mt][nt] = __builtin_amdgcn_mfma_f32_16x16x32_f16(
                    af[mt], bf[nt], acc[mt][nt], 0, 0, 0);
    }

    const int cl = lane & 15;
    const int rq = (lane >> 4) * 4;

    if (MODE == 2 && bn >= 2048) {
        #pragma unroll
        for (int mt = 0; mt < 4; mt++) {
            int row0 = bm + wm + mt*16 + rq;
            #pragma unroll
            for (int nt = 0; nt < 4; nt++) {
                int gcol = bn + wn + nt*16 + cl;
                float bv = G.bias[gcol];
                half4_t hv = {(_Float16)(acc[mt][nt][0] + bv),
                              (_Float16)(acc[mt][nt][1] + bv),
                              (_Float16)(acc[mt][nt][2] + bv),
                              (_Float16)(acc[mt][nt][3] + bv)};
                *(half4_t*)((_Float16*)G.C2 + (size_t)(gcol - 2048) * M_ + row0) = hv;
            }
        }
        return;
    }

    #pragma unroll
    for (int mt = 0; mt < 4; mt++) {
        #pragma unroll
        for (int r = 0; r < 4; r++) {
            size_t grow = (size_t)(bm + wm + mt*16 + rq + r);
            #pragma unroll
            for (int nt = 0; nt < 4; nt++) {
                int gcol = bn + wn + nt*16 + cl;
                float v = acc[mt][nt][r] + G.bias[gcol];
                if (MODE == 0)
                    ((float*)G.C)[grow * ldc + gcol] = v;
                else
                    ((_Float16*)G.C)[grow * ldc + gcol] = (_Float16)v;
            }
        }
    }
}

// ---------------------------------------------------------------------------
// Fused fp32 -> fp16 cast for all 8 tensors in one dispatch.
// ---------------------------------------------------------------------------
struct CastArgs {
    const float* s[8];
    _Float16*    d[8];
    int          nb[8];
};

__global__ __launch_bounds__(256) void cast_all(CastArgs a)
{
    int off = blockIdx.x;
    int seg = 0;
    while (off >= a.nb[seg]) { off -= a.nb[seg]; seg++; }
    int i = off * 256 + threadIdx.x;
    float4 v = ((const float4*)a.s[seg])[i];
    half4_t h = {(_Float16)v.x, (_Float16)v.y, (_Float16)v.z, (_Float16)v.w};
    ((half4_t*)a.d[seg])[i] = h;
}

// ---------------------------------------------------------------------------
// MFMA flash attention, LDS-staged K/V (chunk-major), per-wave q-strips.
//   S^T = K Q^T : A-frag = K rows (LDS), B-frag = Q rows (regs, loaded once)
//   PV          : A-frag = P (per-wave 32-j LDS patch), B-frag = vT rows (LDS)
// P patch reused across the two 32-j kc halves (same-wave DS ops are
// processed in order -> no barrier) -> LDS 37.4KB (DK=128) -> 4 blocks/CU.
// No max-subtraction: |s*scale| < ~3, exp2 exact in fp32 (softmax shift-inv).
// NBR=2 merges two branches (blockIdx.z = branch*2 + batch).
// ---------------------------------------------------------------------------
template<int DK, int H, int NBR, bool LOUT>
__global__ __launch_bounds__(256, 4) void flash3(
    const _Float16* __restrict__ qk0, const _Float16* __restrict__ qk1,
    const _Float16* __restrict__ vT0, const _Float16* __restrict__ vT1,
    _Float16* __restrict__ ctx0, _Float16* __restrict__ ctx1,
    float* __restrict__ lout, int win0, int win1)
{
    constexpr int KS  = DK / 32;     // K chunks (k-dim)
    constexpr int DT  = DK / 16;     // PV d-tiles
    constexpr int LDP = 40;          // Ps row stride: 32 j + 8 pad (80B rows)

    // chunk-major: [chunk][row][32 halfs] -> 64B row stride
    __shared__ __align__(16) _Float16 Ks[KS * 64 * 32];  // K tile:  64 j x DK
    __shared__ __align__(16) _Float16 Vs[2 * DK * 32];   // vT tile: DK d x 64 j
    __shared__ __align__(16) _Float16 Ps[4 * 16 * LDP];  // per-wave 16q x 32j
    __shared__ float Lw[64];

    const int t = threadIdx.x, lane = t & 63, w = t >> 6;
    const int fr = lane & 15, g = lane >> 4, k8 = g * 8;
    const int blkQ = blockIdx.x * 64;
    const int qlo  = blkQ + w * 16;             // wave's q strip
    const int h    = blockIdx.y;

    int br, b;
    if (NBR == 2) { br = blockIdx.z >> 1; b = blockIdx.z & 1; }
    else          { br = 0;               b = blockIdx.z;     }

    const _Float16* qk = br ? qk1 : qk0;
    const _Float16* vT = br ? vT1 : vT0;
    _Float16*      ctx = br ? ctx1 : ctx0;
    const int   window = br ? win1 : win0;

    const float sc = ((DK == 128) ? 0.08838834764831845f : 0.125f) * 1.44269504f;

    _Float16* PsW = Ps + w * 16 * LDP;

    // staging lane geometry: lane l -> row l>>2, halfs (l&3)*8 (HW: base + l*16B)
    const int srow = lane >> 2;
    const int scol = (lane & 3) * 8;

    // Q fragments for this wave's strip (loaded once)
    half8_t qf[KS];
    #pragma unroll
    for (int kk = 0; kk < KS; kk++)
        qf[kk] = *(const half8_t*)&qk[(size_t)(b*S_ + qlo + fr)*2048 + h*DK + kk*32 + k8];

    f32x4 O[DT] = {};
    float lsum = 0.f;

    for (int j0 = 0; j0 < S_; j0 += 64) {
        if (window >= 0 && j0 + 63 < blkQ - window) continue;  // block-uniform skip
        __syncthreads();   // prev tile's LDS reads done

        // ---- stage K: wave w covers rows w*16..+15 of each chunk ----
        #pragma unroll
        for (int kk = 0; kk < KS; kk++)
            GL2LDS(&qk[(size_t)(b*S_ + j0 + w*16 + srow)*2048 + 1024 + h*DK + kk*32 + scol],
                   &Ks[kk*2048 + w*512]);
        // ---- stage vT: wave w covers d-rows w*(DK/4).. of each j-chunk ----
        #pragma unroll
        for (int jc = 0; jc < 2; jc++)
            #pragma unroll
            for (int ii = 0; ii < DK/64; ii++)
                GL2LDS(&vT[(size_t)(h*DK + w*(DK/4) + ii*16 + srow)*M_
                           + b*S_ + j0 + jc*32 + scol],
                       &Vs[jc*DK*32 + w*(DK/4)*32 + ii*512]);
        __syncthreads();   // staging visible

        // ---- scores S^T[j][q] over 4 j-subtiles ----
        f32x4 st[4];
        #pragma unroll
        for (int jt = 0; jt < 4; jt++) {
            f32x4 s = {};
            #pragma unroll
            for (int kk = 0; kk < KS; kk++) {
                half8_t kf = *(const half8_t*)&Ks[kk*2048 + (jt*16 + fr)*32 + k8];
                s = __builtin_amdgcn_mfma_f32_16x16x32_f16(kf, qf[kk], s, 0, 0, 0);
            }
            st[jt] = s;
        }

        // ---- per-kc: exp+mask+pack 32 j into patch, then PV on that half ----
        const bool full = (window < 0) || (j0 >= qlo + 15 - window);
        #pragma unroll
        for (int kc = 0; kc < 2; kc++) {
            #pragma unroll
            for (int jh = 0; jh < 2; jh++) {
                int jt = kc*2 + jh;
                float p[4];
                #pragma unroll
                for (int r = 0; r < 4; r++) {
                    float pv = exp2f(st[jt][r] * sc);
                    if (!full) {
                        int jg = j0 + jt*16 + g*4 + r;
                        if (jg < (qlo + fr) - window) pv = 0.f;
                    }
                    p[r] = pv;
                    lsum += pv;
                }
                half4_t ph = {(_Float16)p[0], (_Float16)p[1],
                              (_Float16)p[2], (_Float16)p[3]};
                *(half4_t*)&PsW[fr*LDP + jh*16 + g*4] = ph;
            }
            // same-wave DS ordering: writes above are serviced before this
            // read, and this read before next kc's overwrites.
            half8_t pf = *(const half8_t*)&PsW[fr*LDP + k8];
            #pragma unroll
            for (int dt = 0; dt < DT; dt++) {
                half8_t vf = *(const half8_t*)&Vs[kc*DK*32 + (dt*16 + fr)*32 + k8];
                O[dt] = __builtin_amdgcn_mfma_f32_16x16x32_f16(pf, vf, O[dt], 0, 0, 0);
            }
        }
    }

    // ---- per-q row sums (reduce g-groups, remap lanes via wave-local LDS) ----
    lsum += __shfl_xor(lsum, 16);
    lsum += __shfl_xor(lsum, 32);
    if (g == 0) Lw[w*16 + fr] = lsum;
    float linv[4];
    #pragma unroll
    for (int r = 0; r < 4; r++)
        linv[r] = 1.f / Lw[w*16 + g*4 + r];

    if (LOUT && g == 0)
        lout[(size_t)(b*H + h)*S_ + qlo + fr] = lsum;

    // ---- epilogue: ctx = O / l (O row=g*4+reg=q, col=fr=d-sub) ----
    #pragma unroll
    for (int r = 0; r < 4; r++) {
        _Float16* cp = ctx + (size_t)(b*S_ + qlo + g*4 + r)*D_ + h*DK;
        #pragma unroll
        for (int dt = 0; dt < DT; dt++)
            cp[dt*16 + fr] = (_Float16)(O[dt][r] * linv[r]);
    }
}

// ---------------------------------------------------------------------------
// Head-averaged long-branch attention probabilities; K staged 2 heads per
// barrier round (32KB LDS, half the barriers):
//   attn[b,i,j] = sum_h exp2(s_h*c1 - log2(l_h,i) - 4)
// Block = 64i x 128j; wave owns 16 i-rows; Q frags direct (once per head).
// ---------------------------------------------------------------------------
__global__ __launch_bounds__(256, 4) void attn_mean3(
    const _Float16* __restrict__ qk,   // long-branch [M_][2048]
    const float* __restrict__ lbuf,    // [B_*16*S_]
    float* __restrict__ attn)          // [B_,S_,S_]
{
    __shared__ __align__(16) _Float16 Ks[2 * 2 * 128 * 32];  // [head][chunk][jrow][32]

    const int t = threadIdx.x, lane = t & 63, w = t >> 6;
    const int fr = lane & 15, g = lane >> 4, k8 = g * 8;
    const int j0 = blockIdx.x * 128;
    const int irow = blockIdx.y * 64 + w * 16;
    const int b = blockIdx.z;
    const float c1 = 0.125f * 1.44269504f;
    const int srow = lane >> 2, scol = (lane & 3) * 8;

    f32x4 acc[8] = {};

    for (int hp = 0; hp < 16; hp += 2) {
        __syncthreads();   // prev round's reads done
        #pragma unroll
        for (int hh = 0; hh < 2; hh++)
            #pragma unroll
            for (int kk = 0; kk < 2; kk++)
                #pragma unroll
                for (int ii = 0; ii < 2; ii++)
                    GL2LDS(&qk[(size_t)(b*S_ + j0 + w*32 + ii*16 + srow)*2048
                               + 1024 + (hp+hh)*64 + kk*32 + scol],
                           &Ks[hh*8192 + kk*4096 + w*1024 + ii*512]);
        __syncthreads();

        #pragma unroll
        for (int hh = 0; hh < 2; hh++) {
            const int h = hp + hh;
            half8_t af[2];
            #pragma unroll
            for (int kk = 0; kk < 2; kk++)
                af[kk] = *(const half8_t*)
                    &qk[(size_t)(b*S_ + irow + fr)*2048 + h*64 + kk*32 + k8];

            float lg[4];
            #pragma unroll
            for (int r = 0; r < 4; r++)
                lg[r] = __log2f(lbuf[(size_t)(b*16 + h)*S_ + irow + g*4 + r]) + 4.0f;

            #pragma unroll
            for (int nt = 0; nt < 8; nt++) {
                f32x4 s = {};
                #pragma unroll
                for (int kk = 0; kk < 2; kk++) {
                    half8_t bf = *(const half8_t*)
                        &Ks[hh*8192 + kk*4096 + (nt*16 + fr)*32 + k8];
                    s = __builtin_amdgcn_mfma_f32_16x16x32_f16(af[kk], bf, s, 0, 0, 0);
                }
                #pragma unroll
                for (int r = 0; r < 4; r++)
                    acc[nt][r] += exp2f(s[r] * c1 - lg[r]);
            }
        }
    }

    #pragma unroll
    for (int r = 0; r < 4; r++) {
        float* p = attn + (size_t)(b*S_ + irow + g*4 + r)*S_ + j0;
        #pragma unroll
        for (int nt = 0; nt < 8; nt++)
            p[nt*16 + fr] = acc[nt][r];
    }
}

// ---------------------------------------------------------------------------
// Residual + LayerNorm
// ---------------------------------------------------------------------------
__global__ __launch_bounds__(256) void ln_residual(
    const float* __restrict__ pre, const float* __restrict__ x,
    const float* __restrict__ gamma, const float* __restrict__ beta,
    float* __restrict__ out)
{
    __shared__ float redS[4], redQ[4];
    const int row = blockIdx.x;
    const int t = threadIdx.x;
    size_t base = (size_t)row * D_ + t * 4;

    float4 v  = *(const float4*)(pre + base);
    float4 xv = *(const float4*)(x + base);
    v.x += xv.x; v.y += xv.y; v.z += xv.z; v.w += xv.w;

    float s = v.x + v.y + v.z + v.w;
    float q = v.x*v.x + v.y*v.y + v.z*v.z + v.w*v.w;
    #pragma unroll
    for (int m = 32; m >= 1; m >>= 1) {
        s += __shfl_xor(s, m);
        q += __shfl_xor(q, m);
    }
    int wave = t >> 6;
    if ((t & 63) == 0) { redS[wave] = s; redQ[wave] = q; }
    __syncthreads();
    s = redS[0] + redS[1] + redS[2] + redS[3];
    q = redQ[0] + redQ[1] + redQ[2] + redQ[3];

    float mean = s * (1.f / D_);
    float var  = q * (1.f / D_) - mean * mean;
    float rstd = rsqrtf(var + 1e-5f);

    float4 g  = *(const float4*)(gamma + t * 4);
    float4 be = *(const float4*)(beta + t * 4);
    float4 o;
    o.x = (v.x - mean) * rstd * g.x + be.x;
    o.y = (v.y - mean) * rstd * g.y + be.y;
    o.z = (v.z - mean) * rstd * g.z + be.z;
    o.w = (v.w - mean) * rstd * g.w + be.w;
    *(float4*)(out + base) = o;
}

// ---------------------------------------------------------------------------
extern "C" void kernel_launch(void* const* d_in, const int* in_sizes, int n_in,
                              void* d_out, int out_size, void* d_ws, size_t ws_size,
                              hipStream_t stream)
{
    (void)in_sizes; (void)n_in; (void)out_size; (void)ws_size;
    const float* x      = (const float*)d_in[0];
    const float* w_in_s = (const float*)d_in[1];
    const float* b_in_s = (const float*)d_in[2];
    const float* wo_s   = (const float*)d_in[3];
    const float* bo_s   = (const float*)d_in[4];
    const float* w_in_m = (const float*)d_in[5];
    const float* b_in_m = (const float*)d_in[6];
    const float* wo_m   = (const float*)d_in[7];
    const float* bo_m   = (const float*)d_in[8];
    const float* w_in_l = (const float*)d_in[9];
    const float* b_in_l = (const float*)d_in[10];
    const float* wo_l   = (const float*)d_in[11];
    const float* bo_l   = (const float*)d_in[12];
    const float* w_comb = (const float*)d_in[13];
    const float* b_comb = (const float*)d_in[14];
    const float* gamma  = (const float*)d_in[15];
    const float* beta   = (const float*)d_in[16];

    float* out    = (float*)d_out;                 // [B,S,D]
    float* attn_o = out + (size_t)M_ * D_;         // [B,S,S]

    // Workspace layout (byte offsets; total ~132 MB).
    // Alias lifetimes (stream order): qk_s,vT_s dead after flash_sm ->
    // reused by long branch. x_h dead after qkv_l gemm -> reused as ctx_l
    // (flash_l writes it strictly after). qk_m dead after flash_sm -> pre.
    char* W = (char*)d_ws;
    _Float16* qk_s   = (_Float16*)(W);               // 16MB  (reused: qk_l)
    _Float16* qk_m   = (_Float16*)(W + 16777216);    // 16MB  (reused: pre fp32)
    _Float16* vT_s   = (_Float16*)(W + 33554432);    //  8MB  (reused: vT_l)
    _Float16* vT_m   = (_Float16*)(W + 41943040);    //  8MB
    _Float16* ctx_s  = (_Float16*)(W + 50331648);    //  8MB
    _Float16* ctx_m  = (_Float16*)(W + 58720256);    //  8MB
    _Float16* comb_h = (_Float16*)(W + 67108864);    // 24MB
    float*    lbuf   = (float*)   (W + 92274688);    // 256KB
    _Float16* x_h    = (_Float16*)(W + 92536832);    //  8MB  (reused: ctx_l)
    _Float16* wpool  = (_Float16*)(W + 100925440);   // ~31MB
    _Float16* qk_l   = qk_s;
    _Float16* vT_l   = vT_s;
    _Float16* ctx_l  = x_h;            // NOT ctx_s: outproj_s reads ctx_s after flash_l
    float*    pre    = (float*)qk_m;

    _Float16* w_in_s_h = wpool;
    _Float16* w_in_m_h = wpool + 3145728;
    _Float16* w_in_l_h = wpool + 6291456;
    _Float16* wo_s_h   = wpool + 9437184;
    _Float16* wo_m_h   = wpool + 10485760;
    _Float16* wo_l_h   = wpool + 11534336;
    _Float16* w_comb_h = wpool + 12582912;

    dim3 blk(256);
    GemmBatch nil = { nullptr, nullptr, nullptr, nullptr, nullptr };

    // ---- fused casts (fp32 -> fp16) ----
    CastArgs ca;
    ca.s[0]=x;      ca.d[0]=x_h;      ca.nb[0]=4096;
    ca.s[1]=w_in_s; ca.d[1]=w_in_s_h; ca.nb[1]=3072;
    ca.s[2]=w_in_m; ca.d[2]=w_in_m_h; ca.nb[2]=3072;
    ca.s[3]=w_in_l; ca.d[3]=w_in_l_h; ca.nb[3]=3072;
    ca.s[4]=wo_s;   ca.d[4]=wo_s_h;   ca.nb[4]=1024;
    ca.s[5]=wo_m;   ca.d[5]=wo_m_h;   ca.nb[5]=1024;
    ca.s[6]=wo_l;   ca.d[6]=wo_l_h;   ca.nb[6]=1024;
    ca.s[7]=w_comb; ca.d[7]=w_comb_h; ca.nb[7]=3072;
    cast_all<<<dim3(19456), blk, 0, stream>>>(ca);

    // ---- QKV projections, short+medium ----
    GemmBatch qs = { x_h, w_in_s_h, b_in_s, qk_s, vT_s };
    GemmBatch qm = { x_h, w_in_m_h, b_in_m, qk_m, vT_m };
    gemm_f16<2><<<dim3(M_/128, 3072/128, 2), blk, 0, stream>>>(qs, qm, nil, D_, D_, 2048, D_);

    // ---- short+medium flash (z = branch*2 + batch) ----
    flash3<128, 8, 2, false><<<dim3(S_/64, 8, 4), blk, 0, stream>>>(
        qk_s, qk_m, vT_s, vT_m, ctx_s, ctx_m, nullptr, 10, 30);

    // ---- QKV long (qk_l/vT_l alias dead short-branch buffers; last read of x_h) ----
    GemmBatch ql = { x_h, w_in_l_h, b_in_l, qk_l, vT_l };
    gemm_f16<2><<<dim3(M_/128, 3072/128, 1), blk, 0, stream>>>(ql, nil, nil, D_, D_, 2048, D_);

    // ---- long flash (ctx_l = dead x_h region; ctx_s/ctx_m untouched) ----
    flash3<64, 16, 1, true><<<dim3(S_/64, 16, 2), blk, 0, stream>>>(
        qk_l, qk_l, vT_l, vT_l, ctx_l, ctx_l, lbuf, -1, -1);

    // ---- all three out-projections in one dispatch (768 blocks) ----
    GemmBatch ps = { ctx_s, wo_s_h, bo_s, comb_h + 0,    nullptr };
    GemmBatch pm = { ctx_m, wo_m_h, bo_m, comb_h + 1024, nullptr };
    GemmBatch pl = { ctx_l, wo_l_h, bo_l, comb_h + 2048, nullptr };
    gemm_f16<1><<<dim3(M_/128, D_/128, 3), blk, 0, stream>>>(ps, pm, pl, D_, D_, 3072, D_);

    // ---- head-averaged probabilities ----
    attn_mean3<<<dim3(S_/128, S_/64, B_), blk, 0, stream>>>(qk_l, lbuf, attn_o);

    // ---- combine + residual LayerNorm (pre aliases qk_m, dead) ----
    GemmBatch cb = { comb_h, w_comb_h, b_comb, pre, nullptr };
    gemm_f16<0><<<dim3(M_/128, D_/128, 1), blk, 0, stream>>>(cb, nil, nil, 3072, 3072, D_, 3072);
    ln_residual<<<dim3(M_), blk, 0, stream>>>(pre, x, gamma, beta, out);
}

// Round 9
// 632.302 us; speedup vs baseline: 1.9051x; 1.0519x over previous
//
#include <hip/hip_runtime.h>
#include <hip/hip_bf16.h>
#include <math.h>

// Problem constants (fixed by reference)
#define B_ 2
#define S_ 2048
#define D_ 1024
#define M_ (B_*S_)      // 4096 rows
#define CTXLD 3072      // fused ctx row stride: [short | medium | long]

typedef _Float16 half8_t __attribute__((ext_vector_type(8)));
typedef _Float16 half4_t __attribute__((ext_vector_type(4)));
typedef float    f32x4  __attribute__((ext_vector_type(4)));

// async global->LDS: per-lane global addr; HW scatters lane i to (uniform LDS base) + i*16B
#define GL2LDS(g, l) __builtin_amdgcn_global_load_lds( \
    (const __attribute__((address_space(1))) void*)(uintptr_t)(g), \
    (__attribute__((address_space(3))) void*)(l), 16, 0, 0)

// ---------------------------------------------------------------------------
// Batched fp16-MFMA GEMM: C = A @ W^T + bias. BK=64 (2 chunk-major k-chunks
// per barrier round -> half the barriers of BK=32). 128x128 tile, 4 waves.
// MODE 0: C fp32 + bias. MODE 1: C fp16 + bias.
// MODE 2: QKV split (cols<2048 -> qk fp16 ldc; cols>=2048 -> vT transposed).
// MODE 3: C fp16, no bias (Weff prep).
// ---------------------------------------------------------------------------
struct GemmBatch {
    const _Float16* A;
    const _Float16* W;
    const float*    bias;
    void*           C;
    void*           C2;
};

template<int MODE>
__global__ __launch_bounds__(256) void gemm_f16(
    GemmBatch b0, GemmBatch b1, GemmBatch b2, int lda, int ldw, int ldc, int K)
{
    // chunk-major: [kchunk(2)][128 rows][32 halfs] = 16KB each
    __shared__ __align__(16) _Float16 As[2*128*32];
    __shared__ __align__(16) _Float16 Bs[2*128*32];

    const GemmBatch G = (blockIdx.z == 0) ? b0 : ((blockIdx.z == 1) ? b1 : b2);

    const int t = threadIdx.x, lane = t & 63, w = t >> 6;
    const int bm = blockIdx.x * 128, bn = blockIdx.y * 128;
    const int wm = (w >> 1) * 64, wn = (w & 1) * 64;
    const int fr = lane & 15, q8 = (lane >> 4) * 8;
    const int srow = lane >> 2, scol = (lane & 3) * 8;

    f32x4 acc[4][4] = {};

    // wave w stages rows w*32 + ii*16 + srow (ii=0,1) of each k-chunk
    const _Float16* Ab = G.A + (size_t)(bm + w*32 + srow) * lda + scol;
    const _Float16* Wb = G.W + (size_t)(bn + w*32 + srow) * ldw + scol;

    for (int k0 = 0; k0 < K; k0 += 64) {
        __syncthreads();
        #pragma unroll
        for (int kc = 0; kc < 2; kc++)
            #pragma unroll
            for (int ii = 0; ii < 2; ii++) {
                GL2LDS(Ab + (size_t)(ii*16)*lda + k0 + kc*32,
                       As + kc*4096 + w*1024 + ii*512);
                GL2LDS(Wb + (size_t)(ii*16)*ldw + k0 + kc*32,
                       Bs + kc*4096 + w*1024 + ii*512);
            }
        __syncthreads();
        #pragma unroll
        for (int kc = 0; kc < 2; kc++) {
            half8_t af[4], bf[4];
            #pragma unroll
            for (int mt = 0; mt < 4; mt++)
                af[mt] = *(const half8_t*)&As[kc*4096 + (wm + mt*16 + fr)*32 + q8];
            #pragma unroll
            for (int nt = 0; nt < 4; nt++)
                bf[nt] = *(const half8_t*)&Bs[kc*4096 + (wn + nt*16 + fr)*32 + q8];
            #pragma unroll
            for (int mt = 0; mt < 4; mt++)
                #pragma unroll
                for (int nt = 0; nt < 4; nt++)
                    acc[mt][nt] = __builtin_amdgcn_mfma_f32_16x16x32_f16(
                        af[mt], bf[nt], acc[mt][nt], 0, 0, 0);
        }
    }

    const int cl = lane & 15;
    const int rq = (lane >> 4) * 4;

    if (MODE == 2 && bn >= 2048) {
        #pragma unroll
        for (int mt = 0; mt < 4; mt++) {
            int row0 = bm + wm + mt*16 + rq;
            #pragma unroll
            for (int nt = 0; nt < 4; nt++) {
                int gcol = bn + wn + nt*16 + cl;
                float bv = G.bias[gcol];
                half4_t hv = {(_Float16)(acc[mt][nt][0] + bv),
                              (_Float16)(acc[mt][nt][1] + bv),
                              (_Float16)(acc[mt][nt][2] + bv),
                              (_Float16)(acc[mt][nt][3] + bv)};
                *(half4_t*)((_Float16*)G.C2 + (size_t)(gcol - 2048) * M_ + row0) = hv;
            }
        }
        return;
    }

    #pragma unroll
    for (int mt = 0; mt < 4; mt++) {
        #pragma unroll
        for (int r = 0; r < 4; r++) {
            size_t grow = (size_t)(bm + wm + mt*16 + rq + r);
            #pragma unroll
            for (int nt = 0; nt < 4; nt++) {
                int gcol = bn + wn + nt*16 + cl;
                float v = acc[mt][nt][r] + ((MODE == 3) ? 0.f : G.bias[gcol]);
                if (MODE == 0)
                    ((float*)G.C)[grow * ldc + gcol] = v;
                else
                    ((_Float16*)G.C)[grow * ldc + gcol] = (_Float16)v;
            }
        }
    }
}

// ---------------------------------------------------------------------------
// Fused fp32 -> fp16 cast (5 tensors: x, w_in x3, w_comb).
// ---------------------------------------------------------------------------
struct CastArgs {
    const float* s[5];
    _Float16*    d[5];
    int          nb[5];
};

__global__ __launch_bounds__(256) void cast_all(CastArgs a)
{
    int off = blockIdx.x;
    int seg = 0;
    while (seg < 4 && off >= a.nb[seg]) { off -= a.nb[seg]; seg++; }
    int i = off * 256 + threadIdx.x;
    float4 v = ((const float4*)a.s[seg])[i];
    half4_t h = {(_Float16)v.x, (_Float16)v.y, (_Float16)v.z, (_Float16)v.w};
    ((half4_t*)a.d[seg])[i] = h;
}

// ---------------------------------------------------------------------------
// Transposing cast for wo_* : in fp32 [1024 d][1024 e] -> out fp16 [e][d].
// ---------------------------------------------------------------------------
__global__ __launch_bounds__(256) void transpose_cast_wo(
    const float* s0, const float* s1, const float* s2,
    _Float16* d0, _Float16* d1, _Float16* d2)
{
    __shared__ float T[64][68];
    const float* src = blockIdx.z == 0 ? s0 : (blockIdx.z == 1 ? s1 : s2);
    _Float16*    dst = blockIdx.z == 0 ? d0 : (blockIdx.z == 1 ? d1 : d2);
    const int db = blockIdx.x * 64;   // input row block (d)
    const int eb = blockIdx.y * 64;   // input col block (e)
    const int r = threadIdx.x >> 4;          // 0..15
    const int c = (threadIdx.x & 15) * 4;    // 0..60

    #pragma unroll
    for (int rr = 0; rr < 4; rr++) {
        float4 v = *(const float4*)&src[(size_t)(db + rr*16 + r)*1024 + eb + c];
        T[rr*16 + r][c+0] = v.x; T[rr*16 + r][c+1] = v.y;
        T[rr*16 + r][c+2] = v.z; T[rr*16 + r][c+3] = v.w;
    }
    __syncthreads();
    #pragma unroll
    for (int rr = 0; rr < 4; rr++) {
        int e = rr*16 + r;
        half4_t hv = {(_Float16)T[c+0][e], (_Float16)T[c+1][e],
                      (_Float16)T[c+2][e], (_Float16)T[c+3][e]};
        *(half4_t*)&dst[(size_t)(eb + e)*1024 + db + c] = hv;
    }
}

// ---------------------------------------------------------------------------
// beff[n] = b_comb[n] + sum_d bo_s[d] w_comb[n][d] + bo_m[d] w_comb[n][1024+d]
//                     + bo_l[d] w_comb[n][2048+d].   One block per n.
// ---------------------------------------------------------------------------
__global__ __launch_bounds__(256) void beff_kernel(
    const float* __restrict__ w_comb, const float* __restrict__ b_comb,
    const float* __restrict__ bo_s, const float* __restrict__ bo_m,
    const float* __restrict__ bo_l, float* __restrict__ beff)
{
    __shared__ float red[4];
    const int n = blockIdx.x, t = threadIdx.x;
    float s = 0.f;
    for (int d = t; d < 1024; d += 256)
        s += w_comb[(size_t)n*3072 + d]        * bo_s[d]
           + w_comb[(size_t)n*3072 + 1024 + d] * bo_m[d]
           + w_comb[(size_t)n*3072 + 2048 + d] * bo_l[d];
    #pragma unroll
    for (int m = 32; m >= 1; m >>= 1) s += __shfl_xor(s, m);
    if ((t & 63) == 0) red[t >> 6] = s;
    __syncthreads();
    if (t == 0) beff[n] = b_comb[n] + red[0] + red[1] + red[2] + red[3];
}

// ---------------------------------------------------------------------------
// MFMA flash attention, LDS-staged K/V (chunk-major), per-wave q-strips.
// ctx written into the fused ctxall [M_][3072] (branch column offset in ptr).
// ---------------------------------------------------------------------------
template<int DK, int H, int NBR, bool LOUT>
__global__ __launch_bounds__(256, 4) void flash3(
    const _Float16* __restrict__ qk0, const _Float16* __restrict__ qk1,
    const _Float16* __restrict__ vT0, const _Float16* __restrict__ vT1,
    _Float16* __restrict__ ctx0, _Float16* __restrict__ ctx1,
    float* __restrict__ lout, int win0, int win1)
{
    constexpr int KS  = DK / 32;     // K chunks (k-dim)
    constexpr int DT  = DK / 16;     // PV d-tiles
    constexpr int LDP = 40;          // Ps row stride: 32 j + 8 pad

    __shared__ __align__(16) _Float16 Ks[KS * 64 * 32];
    __shared__ __align__(16) _Float16 Vs[2 * DK * 32];
    __shared__ __align__(16) _Float16 Ps[4 * 16 * LDP];
    __shared__ float Lw[64];

    const int t = threadIdx.x, lane = t & 63, w = t >> 6;
    const int fr = lane & 15, g = lane >> 4, k8 = g * 8;
    const int blkQ = blockIdx.x * 64;
    const int qlo  = blkQ + w * 16;
    const int h    = blockIdx.y;

    int br, b;
    if (NBR == 2) { br = blockIdx.z >> 1; b = blockIdx.z & 1; }
    else          { br = 0;               b = blockIdx.z;     }

    const _Float16* qk = br ? qk1 : qk0;
    const _Float16* vT = br ? vT1 : vT0;
    _Float16*      ctx = br ? ctx1 : ctx0;
    const int   window = br ? win1 : win0;

    const float sc = ((DK == 128) ? 0.08838834764831845f : 0.125f) * 1.44269504f;

    _Float16* PsW = Ps + w * 16 * LDP;
    const int srow = lane >> 2;
    const int scol = (lane & 3) * 8;

    half8_t qf[KS];
    #pragma unroll
    for (int kk = 0; kk < KS; kk++)
        qf[kk] = *(const half8_t*)&qk[(size_t)(b*S_ + qlo + fr)*2048 + h*DK + kk*32 + k8];

    f32x4 O[DT] = {};
    float lsum = 0.f;

    for (int j0 = 0; j0 < S_; j0 += 64) {
        if (window >= 0 && j0 + 63 < blkQ - window) continue;
        __syncthreads();

        #pragma unroll
        for (int kk = 0; kk < KS; kk++)
            GL2LDS(&qk[(size_t)(b*S_ + j0 + w*16 + srow)*2048 + 1024 + h*DK + kk*32 + scol],
                   &Ks[kk*2048 + w*512]);
        #pragma unroll
        for (int jc = 0; jc < 2; jc++)
            #pragma unroll
            for (int ii = 0; ii < DK/64; ii++)
                GL2LDS(&vT[(size_t)(h*DK + w*(DK/4) + ii*16 + srow)*M_
                           + b*S_ + j0 + jc*32 + scol],
                       &Vs[jc*DK*32 + w*(DK/4)*32 + ii*512]);
        __syncthreads();

        f32x4 st[4];
        #pragma unroll
        for (int jt = 0; jt < 4; jt++) {
            f32x4 s = {};
            #pragma unroll
            for (int kk = 0; kk < KS; kk++) {
                half8_t kf = *(const half8_t*)&Ks[kk*2048 + (jt*16 + fr)*32 + k8];
                s = __builtin_amdgcn_mfma_f32_16x16x32_f16(kf, qf[kk], s, 0, 0, 0);
            }
            st[jt] = s;
        }

        const bool full = (window < 0) || (j0 >= qlo + 15 - window);
        #pragma unroll
        for (int kc = 0; kc < 2; kc++) {
            #pragma unroll
            for (int jh = 0; jh < 2; jh++) {
                int jt = kc*2 + jh;
                float p[4];
                #pragma unroll
                for (int r = 0; r < 4; r++) {
                    float pv = exp2f(st[jt][r] * sc);
                    if (!full) {
                        int jg = j0 + jt*16 + g*4 + r;
                        if (jg < (qlo + fr) - window) pv = 0.f;
                    }
                    p[r] = pv;
                    lsum += pv;
                }
                half4_t ph = {(_Float16)p[0], (_Float16)p[1],
                              (_Float16)p[2], (_Float16)p[3]};
                *(half4_t*)&PsW[fr*LDP + jh*16 + g*4] = ph;
            }
            half8_t pf = *(const half8_t*)&PsW[fr*LDP + k8];
            #pragma unroll
            for (int dt = 0; dt < DT; dt++) {
                half8_t vf = *(const half8_t*)&Vs[kc*DK*32 + (dt*16 + fr)*32 + k8];
                O[dt] = __builtin_amdgcn_mfma_f32_16x16x32_f16(pf, vf, O[dt], 0, 0, 0);
            }
        }
    }

    lsum += __shfl_xor(lsum, 16);
    lsum += __shfl_xor(lsum, 32);
    if (g == 0) Lw[w*16 + fr] = lsum;
    float linv[4];
    #pragma unroll
    for (int r = 0; r < 4; r++)
        linv[r] = 1.f / Lw[w*16 + g*4 + r];

    if (LOUT && g == 0)
        lout[(size_t)(b*H + h)*S_ + qlo + fr] = lsum;

    #pragma unroll
    for (int r = 0; r < 4; r++) {
        _Float16* cp = ctx + (size_t)(b*S_ + qlo + g*4 + r)*CTXLD + h*DK;
        #pragma unroll
        for (int dt = 0; dt < DT; dt++)
            cp[dt*16 + fr] = (_Float16)(O[dt][r] * linv[r]);
    }
}

// ---------------------------------------------------------------------------
// Head-averaged long-branch attention probabilities (2 heads per barrier).
// ---------------------------------------------------------------------------
__global__ __launch_bounds__(256, 4) void attn_mean3(
    const _Float16* __restrict__ qk,
    const float* __restrict__ lbuf,
    float* __restrict__ attn)
{
    __shared__ __align__(16) _Float16 Ks[2 * 2 * 128 * 32];

    const int t = threadIdx.x, lane = t & 63, w = t >> 6;
    const int fr = lane & 15, g = lane >> 4, k8 = g * 8;
    const int j0 = blockIdx.x * 128;
    const int irow = blockIdx.y * 64 + w * 16;
    const int b = blockIdx.z;
    const float c1 = 0.125f * 1.44269504f;
    const int srow = lane >> 2, scol = (lane & 3) * 8;

    f32x4 acc[8] = {};

    for (int hp = 0; hp < 16; hp += 2) {
        __syncthreads();
        #pragma unroll
        for (int hh = 0; hh < 2; hh++)
            #pragma unroll
            for (int kk = 0; kk < 2; kk++)
                #pragma unroll
                for (int ii = 0; ii < 2; ii++)
                    GL2LDS(&qk[(size_t)(b*S_ + j0 + w*32 + ii*16 + srow)*2048
                               + 1024 + (hp+hh)*64 + kk*32 + scol],
                           &Ks[hh*8192 + kk*4096 + w*1024 + ii*512]);
        __syncthreads();

        #pragma unroll
        for (int hh = 0; hh < 2; hh++) {
            const int h = hp + hh;
            half8_t af[2];
            #pragma unroll
            for (int kk = 0; kk < 2; kk++)
                af[kk] = *(const half8_t*)
                    &qk[(size_t)(b*S_ + irow + fr)*2048 + h*64 + kk*32 + k8];

            float lg[4];
            #pragma unroll
            for (int r = 0; r < 4; r++)
                lg[r] = __log2f(lbuf[(size_t)(b*16 + h)*S_ + irow + g*4 + r]) + 4.0f;

            #pragma unroll
            for (int nt = 0; nt < 8; nt++) {
                f32x4 s = {};
                #pragma unroll
                for (int kk = 0; kk < 2; kk++) {
                    half8_t bf = *(const half8_t*)
                        &Ks[hh*8192 + kk*4096 + (nt*16 + fr)*32 + k8];
                    s = __builtin_amdgcn_mfma_f32_16x16x32_f16(af[kk], bf, s, 0, 0, 0);
                }
                #pragma unroll
                for (int r = 0; r < 4; r++)
                    acc[nt][r] += exp2f(s[r] * c1 - lg[r]);
            }
        }
    }

    #pragma unroll
    for (int r = 0; r < 4; r++) {
        float* p = attn + (size_t)(b*S_ + irow + g*4 + r)*S_ + j0;
        #pragma unroll
        for (int nt = 0; nt < 8; nt++)
            p[nt*16 + fr] = acc[nt][r];
    }
}

// ---------------------------------------------------------------------------
// Residual + LayerNorm
// ---------------------------------------------------------------------------
__global__ __launch_bounds__(256) void ln_residual(
    const float* __restrict__ pre, const float* __restrict__ x,
    const float* __restrict__ gamma, const float* __restrict__ beta,
    float* __restrict__ out)
{
    __shared__ float redS[4], redQ[4];
    const int row = blockIdx.x;
    const int t = threadIdx.x;
    size_t base = (size_t)row * D_ + t * 4;

    float4 v  = *(const float4*)(pre + base);
    float4 xv = *(const float4*)(x + base);
    v.x += xv.x; v.y += xv.y; v.z += xv.z; v.w += xv.w;

    float s = v.x + v.y + v.z + v.w;
    float q = v.x*v.x + v.y*v.y + v.z*v.z + v.w*v.w;
    #pragma unroll
    for (int m = 32; m >= 1; m >>= 1) {
        s += __shfl_xor(s, m);
        q += __shfl_xor(q, m);
    }
    int wave = t >> 6;
    if ((t & 63) == 0) { redS[wave] = s; redQ[wave] = q; }
    __syncthreads();
    s = redS[0] + redS[1] + redS[2] + redS[3];
    q = redQ[0] + redQ[1] + redQ[2] + redQ[3];

    float mean = s * (1.f / D_);
    float var  = q * (1.f / D_) - mean * mean;
    float rstd = rsqrtf(var + 1e-5f);

    float4 g  = *(const float4*)(gamma + t * 4);
    float4 be = *(const float4*)(beta + t * 4);
    float4 o;
    o.x = (v.x - mean) * rstd * g.x + be.x;
    o.y = (v.y - mean) * rstd * g.y + be.y;
    o.z = (v.z - mean) * rstd * g.z + be.z;
    o.w = (v.w - mean) * rstd * g.w + be.w;
    *(float4*)(out + base) = o;
}

// ---------------------------------------------------------------------------
extern "C" void kernel_launch(void* const* d_in, const int* in_sizes, int n_in,
                              void* d_out, int out_size, void* d_ws, size_t ws_size,
                              hipStream_t stream)
{
    (void)in_sizes; (void)n_in; (void)out_size; (void)ws_size;
    const float* x      = (const float*)d_in[0];
    const float* w_in_s = (const float*)d_in[1];
    const float* b_in_s = (const float*)d_in[2];
    const float* wo_s   = (const float*)d_in[3];
    const float* bo_s   = (const float*)d_in[4];
    const float* w_in_m = (const float*)d_in[5];
    const float* b_in_m = (const float*)d_in[6];
    const float* wo_m   = (const float*)d_in[7];
    const float* bo_m   = (const float*)d_in[8];
    const float* w_in_l = (const float*)d_in[9];
    const float* b_in_l = (const float*)d_in[10];
    const float* wo_l   = (const float*)d_in[11];
    const float* bo_l   = (const float*)d_in[12];
    const float* w_comb = (const float*)d_in[13];
    const float* b_comb = (const float*)d_in[14];
    const float* gamma  = (const float*)d_in[15];
    const float* beta   = (const float*)d_in[16];

    float* out    = (float*)d_out;                 // [B,S,D]
    float* attn_o = out + (size_t)M_ * D_;         // [B,S,S]

    // Workspace layout (byte offsets; total ~122 MB).
    // Alias lifetimes (stream order): qk_s/vT_s dead after flash_sm -> long
    // branch; qk_m dead after flash_sm -> pre (written by final GEMM).
    char* W = (char*)d_ws;
    _Float16* qk_s   = (_Float16*)(W);               // 16MB  (-> qk_l)
    _Float16* qk_m   = (_Float16*)(W + 16777216);    // 16MB  (-> pre fp32)
    _Float16* vT_s   = (_Float16*)(W + 33554432);    //  8MB  (-> vT_l)
    _Float16* vT_m   = (_Float16*)(W + 41943040);    //  8MB
    _Float16* ctxall = (_Float16*)(W + 50331648);    // 24MB  [4096][3072]
    float*    lbuf   = (float*)   (W + 75497472);    // 256KB
    _Float16* x_h    = (_Float16*)(W + 75759616);    //  8MB
    _Float16* wpool  = (_Float16*)(W + 84148224);    // ~37MB
    float*    beff   = (float*)   (W + 121896960);   //  4KB
    _Float16* qk_l   = qk_s;
    _Float16* vT_l   = vT_s;
    float*    pre    = (float*)qk_m;

    _Float16* w_in_s_h = wpool;                       // 3145728 halfs
    _Float16* w_in_m_h = wpool + 3145728;
    _Float16* w_in_l_h = wpool + 6291456;
    _Float16* w_comb_h = wpool + 9437184;             // [1024][3072]
    _Float16* woT_s    = wpool + 12582912;            // [1024][1024] each
    _Float16* woT_m    = wpool + 13631488;
    _Float16* woT_l    = wpool + 14680064;
    _Float16* weff     = wpool + 15728640;            // [1024][3072]

    dim3 blk(256);
    GemmBatch nil = { nullptr, nullptr, nullptr, nullptr, nullptr };

    // ---- casts: x, w_in x3, w_comb (one dispatch) ----
    CastArgs ca;
    ca.s[0]=x;      ca.d[0]=x_h;      ca.nb[0]=4096;
    ca.s[1]=w_in_s; ca.d[1]=w_in_s_h; ca.nb[1]=3072;
    ca.s[2]=w_in_m; ca.d[2]=w_in_m_h; ca.nb[2]=3072;
    ca.s[3]=w_in_l; ca.d[3]=w_in_l_h; ca.nb[3]=3072;
    ca.s[4]=w_comb; ca.d[4]=w_comb_h; ca.nb[4]=3072;
    cast_all<<<dim3(16384), blk, 0, stream>>>(ca);

    // ---- transpose-cast wo_* -> woT_* ----
    transpose_cast_wo<<<dim3(16, 16, 3), blk, 0, stream>>>(
        wo_s, wo_m, wo_l, woT_s, woT_m, woT_l);

    // ---- Weff_b = Wc_b @ wo_b  (fp16, no bias), stored at weff col b*1024 ----
    GemmBatch we0 = { w_comb_h + 0,    woT_s, nullptr, weff + 0,    nullptr };
    GemmBatch we1 = { w_comb_h + 1024, woT_m, nullptr, weff + 1024, nullptr };
    GemmBatch we2 = { w_comb_h + 2048, woT_l, nullptr, weff + 2048, nullptr };
    gemm_f16<3><<<dim3(8, 8, 3), blk, 0, stream>>>(we0, we1, we2, 3072, 1024, 3072, 1024);

    // ---- beff = b_comb + Wc . bo_cat ----
    beff_kernel<<<dim3(1024), blk, 0, stream>>>(w_comb, b_comb, bo_s, bo_m, bo_l, beff);

    // ---- QKV projections, short+medium ----
    GemmBatch qs = { x_h, w_in_s_h, b_in_s, qk_s, vT_s };
    GemmBatch qm = { x_h, w_in_m_h, b_in_m, qk_m, vT_m };
    gemm_f16<2><<<dim3(M_/128, 3072/128, 2), blk, 0, stream>>>(qs, qm, nil, D_, D_, 2048, D_);

    // ---- short+medium flash -> ctxall cols [0,1024) and [1024,2048) ----
    flash3<128, 8, 2, false><<<dim3(S_/64, 8, 4), blk, 0, stream>>>(
        qk_s, qk_m, vT_s, vT_m, ctxall + 0, ctxall + 1024, nullptr, 10, 30);

    // ---- QKV long (aliases dead short-branch buffers) ----
    GemmBatch ql = { x_h, w_in_l_h, b_in_l, qk_l, vT_l };
    gemm_f16<2><<<dim3(M_/128, 3072/128, 1), blk, 0, stream>>>(ql, nil, nil, D_, D_, 2048, D_);

    // ---- long flash -> ctxall cols [2048,3072) + lbuf ----
    flash3<64, 16, 1, true><<<dim3(S_/64, 16, 2), blk, 0, stream>>>(
        qk_l, qk_l, vT_l, vT_l, ctxall + 2048, ctxall + 2048, lbuf, -1, -1);

    // ---- head-averaged probabilities ----
    attn_mean3<<<dim3(S_/128, S_/64, B_), blk, 0, stream>>>(qk_l, lbuf, attn_o);

    // ---- fused (outproj+combine): pre = ctxall @ weff^T + beff ----
    GemmBatch fb = { ctxall, weff, beff, pre, nullptr };
    gemm_f16<0><<<dim3(M_/128, D_/128, 1), blk, 0, stream>>>(fb, nil, nil, 3072, 3072, D_, 3072);

    // ---- residual LayerNorm ----
    ln_residual<<<dim3(M_), blk, 0, stream>>>(pre, x, gamma, beta, out);
}

// Round 10
// 609.672 us; speedup vs baseline: 1.9759x; 1.0371x over previous
//
#include <hip/hip_runtime.h>
#include <hip/hip_bf16.h>
#include <math.h>

// Problem constants (fixed by reference)
#define B_ 2
#define S_ 2048
#define D_ 1024
#define M_ (B_*S_)      // 4096 rows
#define CTXLD 3072      // fused ctx row stride: [short | medium | long]

typedef _Float16 half8_t __attribute__((ext_vector_type(8)));
typedef _Float16 half4_t __attribute__((ext_vector_type(4)));
typedef float    f32x4  __attribute__((ext_vector_type(4)));

// async global->LDS: per-lane global addr; HW scatters lane i to (uniform LDS base) + i*16B
#define GL2LDS(g, l) __builtin_amdgcn_global_load_lds( \
    (const __attribute__((address_space(1))) void*)(uintptr_t)(g), \
    (__attribute__((address_space(3))) void*)(l), 16, 0, 0)

// ---------------------------------------------------------------------------
// Batched fp16-MFMA GEMM: C = A @ W^T + bias. BK=64 chunk-major.
// 128x128 tile, 4 waves. blockIdx.z selects batch {b0,b1,b2}.
// MODE 0: C fp32 + bias. MODE 1: C fp16 + bias.
// MODE 2: QKV split (cols<2048 -> qk fp16 ldc; cols>=2048 -> vT transposed).
// MODE 3: C fp16, no bias (Weff prep).
// ---------------------------------------------------------------------------
struct GemmBatch {
    const _Float16* A;
    const _Float16* W;
    const float*    bias;
    void*           C;
    void*           C2;
};

template<int MODE>
__global__ __launch_bounds__(256) void gemm_f16(
    GemmBatch b0, GemmBatch b1, GemmBatch b2, int lda, int ldw, int ldc, int K)
{
    __shared__ __align__(16) _Float16 As[2*128*32];
    __shared__ __align__(16) _Float16 Bs[2*128*32];

    const GemmBatch G = (blockIdx.z == 0) ? b0 : ((blockIdx.z == 1) ? b1 : b2);

    const int t = threadIdx.x, lane = t & 63, w = t >> 6;
    const int bm = blockIdx.x * 128, bn = blockIdx.y * 128;
    const int wm = (w >> 1) * 64, wn = (w & 1) * 64;
    const int fr = lane & 15, q8 = (lane >> 4) * 8;
    const int srow = lane >> 2, scol = (lane & 3) * 8;

    f32x4 acc[4][4] = {};

    const _Float16* Ab = G.A + (size_t)(bm + w*32 + srow) * lda + scol;
    const _Float16* Wb = G.W + (size_t)(bn + w*32 + srow) * ldw + scol;

    for (int k0 = 0; k0 < K; k0 += 64) {
        __syncthreads();
        #pragma unroll
        for (int kc = 0; kc < 2; kc++)
            #pragma unroll
            for (int ii = 0; ii < 2; ii++) {
                GL2LDS(Ab + (size_t)(ii*16)*lda + k0 + kc*32,
                       As + kc*4096 + w*1024 + ii*512);
                GL2LDS(Wb + (size_t)(ii*16)*ldw + k0 + kc*32,
                       Bs + kc*4096 + w*1024 + ii*512);
            }
        __syncthreads();
        #pragma unroll
        for (int kc = 0; kc < 2; kc++) {
            half8_t af[4], bf[4];
            #pragma unroll
            for (int mt = 0; mt < 4; mt++)
                af[mt] = *(const half8_t*)&As[kc*4096 + (wm + mt*16 + fr)*32 + q8];
            #pragma unroll
            for (int nt = 0; nt < 4; nt++)
                bf[nt] = *(const half8_t*)&Bs[kc*4096 + (wn + nt*16 + fr)*32 + q8];
            #pragma unroll
            for (int mt = 0; mt < 4; mt++)
                #pragma unroll
                for (int nt = 0; nt < 4; nt++)
                    acc[mt][nt] = __builtin_amdgcn_mfma_f32_16x16x32_f16(
                        af[mt], bf[nt], acc[mt][nt], 0, 0, 0);
        }
    }

    const int cl = lane & 15;
    const int rq = (lane >> 4) * 4;

    if (MODE == 2 && bn >= 2048) {
        #pragma unroll
        for (int mt = 0; mt < 4; mt++) {
            int row0 = bm + wm + mt*16 + rq;
            #pragma unroll
            for (int nt = 0; nt < 4; nt++) {
                int gcol = bn + wn + nt*16 + cl;
                float bv = G.bias[gcol];
                half4_t hv = {(_Float16)(acc[mt][nt][0] + bv),
                              (_Float16)(acc[mt][nt][1] + bv),
                              (_Float16)(acc[mt][nt][2] + bv),
                              (_Float16)(acc[mt][nt][3] + bv)};
                *(half4_t*)((_Float16*)G.C2 + (size_t)(gcol - 2048) * M_ + row0) = hv;
            }
        }
        return;
    }

    #pragma unroll
    for (int mt = 0; mt < 4; mt++) {
        #pragma unroll
        for (int r = 0; r < 4; r++) {
            size_t grow = (size_t)(bm + wm + mt*16 + rq + r);
            #pragma unroll
            for (int nt = 0; nt < 4; nt++) {
                int gcol = bn + wn + nt*16 + cl;
                float v = acc[mt][nt][r] + ((MODE == 3) ? 0.f : G.bias[gcol]);
                if (MODE == 0)
                    ((float*)G.C)[grow * ldc + gcol] = v;
                else
                    ((_Float16*)G.C)[grow * ldc + gcol] = (_Float16)v;
            }
        }
    }
}

// ---------------------------------------------------------------------------
// Fused fp32 -> fp16 cast (5 tensors: x, w_in x3, w_comb).
// ---------------------------------------------------------------------------
struct CastArgs {
    const float* s[5];
    _Float16*    d[5];
    int          nb[5];
};

__global__ __launch_bounds__(256) void cast_all(CastArgs a)
{
    int off = blockIdx.x;
    int seg = 0;
    while (seg < 4 && off >= a.nb[seg]) { off -= a.nb[seg]; seg++; }
    int i = off * 256 + threadIdx.x;
    float4 v = ((const float4*)a.s[seg])[i];
    half4_t h = {(_Float16)v.x, (_Float16)v.y, (_Float16)v.z, (_Float16)v.w};
    ((half4_t*)a.d[seg])[i] = h;
}

// ---------------------------------------------------------------------------
// Transposing cast for wo_* : in fp32 [1024 d][1024 e] -> out fp16 [e][d].
// ---------------------------------------------------------------------------
__global__ __launch_bounds__(256) void transpose_cast_wo(
    const float* s0, const float* s1, const float* s2,
    _Float16* d0, _Float16* d1, _Float16* d2)
{
    __shared__ float T[64][68];
    const float* src = blockIdx.z == 0 ? s0 : (blockIdx.z == 1 ? s1 : s2);
    _Float16*    dst = blockIdx.z == 0 ? d0 : (blockIdx.z == 1 ? d1 : d2);
    const int db = blockIdx.x * 64;
    const int eb = blockIdx.y * 64;
    const int r = threadIdx.x >> 4;
    const int c = (threadIdx.x & 15) * 4;

    #pragma unroll
    for (int rr = 0; rr < 4; rr++) {
        float4 v = *(const float4*)&src[(size_t)(db + rr*16 + r)*1024 + eb + c];
        T[rr*16 + r][c+0] = v.x; T[rr*16 + r][c+1] = v.y;
        T[rr*16 + r][c+2] = v.z; T[rr*16 + r][c+3] = v.w;
    }
    __syncthreads();
    #pragma unroll
    for (int rr = 0; rr < 4; rr++) {
        int e = rr*16 + r;
        half4_t hv = {(_Float16)T[c+0][e], (_Float16)T[c+1][e],
                      (_Float16)T[c+2][e], (_Float16)T[c+3][e]};
        *(half4_t*)&dst[(size_t)(eb + e)*1024 + db + c] = hv;
    }
}

// ---------------------------------------------------------------------------
// beff[n] = b_comb[n] + sum_d bo_s[d] Wc[n][d] + bo_m[d] Wc[n][1024+d] + bo_l[d] Wc[n][2048+d]
// ---------------------------------------------------------------------------
__global__ __launch_bounds__(256) void beff_kernel(
    const float* __restrict__ w_comb, const float* __restrict__ b_comb,
    const float* __restrict__ bo_s, const float* __restrict__ bo_m,
    const float* __restrict__ bo_l, float* __restrict__ beff)
{
    __shared__ float red[4];
    const int n = blockIdx.x, t = threadIdx.x;
    float s = 0.f;
    for (int d = t; d < 1024; d += 256)
        s += w_comb[(size_t)n*3072 + d]        * bo_s[d]
           + w_comb[(size_t)n*3072 + 1024 + d] * bo_m[d]
           + w_comb[(size_t)n*3072 + 2048 + d] * bo_l[d];
    #pragma unroll
    for (int m = 32; m >= 1; m >>= 1) s += __shfl_xor(s, m);
    if ((t & 63) == 0) red[t >> 6] = s;
    __syncthreads();
    if (t == 0) beff[n] = b_comb[n] + red[0] + red[1] + red[2] + red[3];
}

// ---------------------------------------------------------------------------
// Flash attention body (per-wave q-strips, LDS-staged K/V chunk-major,
// P patch reused per 32-j kc half).  LDS partition (halfs):
//   Ks [0, DK*BJ) | Vs [DK*BJ, 2*DK*BJ) | Ps [2*DK*BJ, +4*16*40)
// DK*BJ = 8192 for both instantiations (128x64 and 64x128) -> 37.9KB total.
// ---------------------------------------------------------------------------
template<int DK, int BJ, bool LOUT>
__device__ __forceinline__ void flash_body(
    _Float16* lds, float* Lw,
    const _Float16* __restrict__ qk, const _Float16* __restrict__ vT,
    _Float16* __restrict__ ctx, float* __restrict__ lout,
    int window, int b, int h, int qblk, int H)
{
    constexpr int KS  = DK / 32;     // k-chunks
    constexpr int DT  = DK / 16;     // PV d-tiles
    constexpr int JT  = BJ / 16;     // j-subtiles per round
    constexpr int JC  = BJ / 32;     // j-chunks per round (PV kc count)
    constexpr int LDP = 40;

    _Float16* Ks = lds;
    _Float16* Vs = lds + DK*BJ;
    _Float16* Ps = lds + 2*DK*BJ;

    const int t = threadIdx.x, lane = t & 63, w = t >> 6;
    const int fr = lane & 15, g = lane >> 4, k8 = g * 8;
    const int blkQ = qblk * 64;
    const int qlo  = blkQ + w * 16;

    const float sc = ((DK == 128) ? 0.08838834764831845f : 0.125f) * 1.44269504f;

    _Float16* PsW = Ps + w * 16 * LDP;
    const int srow = lane >> 2;
    const int scol = (lane & 3) * 8;

    half8_t qf[KS];
    #pragma unroll
    for (int kk = 0; kk < KS; kk++)
        qf[kk] = *(const half8_t*)&qk[(size_t)(b*S_ + qlo + fr)*2048 + h*DK + kk*32 + k8];

    f32x4 O[DT] = {};
    float lsum = 0.f;

    for (int j0 = 0; j0 < S_; j0 += BJ) {
        if (window >= 0 && j0 + BJ - 1 < blkQ - window) continue;
        __syncthreads();

        // stage K: [kchunk][BJ rows][32]; wave w rows w*(BJ/4)+ii*16+srow
        #pragma unroll
        for (int kk = 0; kk < KS; kk++)
            #pragma unroll
            for (int ii = 0; ii < BJ/64; ii++)
                GL2LDS(&qk[(size_t)(b*S_ + j0 + w*(BJ/4) + ii*16 + srow)*2048
                           + 1024 + h*DK + kk*32 + scol],
                       &Ks[kk*BJ*32 + w*(BJ/4)*32 + ii*512]);
        // stage vT: [jchunk][DK rows][32]; wave w d-rows w*(DK/4)+ii*16+srow
        #pragma unroll
        for (int jc = 0; jc < JC; jc++)
            #pragma unroll
            for (int ii = 0; ii < DK/64; ii++)
                GL2LDS(&vT[(size_t)(h*DK + w*(DK/4) + ii*16 + srow)*M_
                           + b*S_ + j0 + jc*32 + scol],
                       &Vs[jc*DK*32 + w*(DK/4)*32 + ii*512]);
        __syncthreads();

        f32x4 st[JT];
        #pragma unroll
        for (int jt = 0; jt < JT; jt++) {
            f32x4 s = {};
            #pragma unroll
            for (int kk = 0; kk < KS; kk++) {
                half8_t kf = *(const half8_t*)&Ks[kk*BJ*32 + (jt*16 + fr)*32 + k8];
                s = __builtin_amdgcn_mfma_f32_16x16x32_f16(kf, qf[kk], s, 0, 0, 0);
            }
            st[jt] = s;
        }

        const bool full = (window < 0) || (j0 >= qlo + 15 - window);
        #pragma unroll
        for (int kc = 0; kc < JC; kc++) {
            #pragma unroll
            for (int jh = 0; jh < 2; jh++) {
                int jt = kc*2 + jh;
                float p[4];
                #pragma unroll
                for (int r = 0; r < 4; r++) {
                    float pv = exp2f(st[jt][r] * sc);
                    if (!full) {
                        int jg = j0 + jt*16 + g*4 + r;
                        if (jg < (qlo + fr) - window) pv = 0.f;
                    }
                    p[r] = pv;
                    lsum += pv;
                }
                half4_t ph = {(_Float16)p[0], (_Float16)p[1],
                              (_Float16)p[2], (_Float16)p[3]};
                *(half4_t*)&PsW[fr*LDP + jh*16 + g*4] = ph;
            }
            // same-wave DS ordering: write -> read -> next overwrite is safe
            half8_t pf = *(const half8_t*)&PsW[fr*LDP + k8];
            #pragma unroll
            for (int dt = 0; dt < DT; dt++) {
                half8_t vf = *(const half8_t*)&Vs[kc*DK*32 + (dt*16 + fr)*32 + k8];
                O[dt] = __builtin_amdgcn_mfma_f32_16x16x32_f16(pf, vf, O[dt], 0, 0, 0);
            }
        }
    }

    lsum += __shfl_xor(lsum, 16);
    lsum += __shfl_xor(lsum, 32);
    if (g == 0) Lw[w*16 + fr] = lsum;
    float linv[4];
    #pragma unroll
    for (int r = 0; r < 4; r++)
        linv[r] = 1.f / Lw[w*16 + g*4 + r];

    if (LOUT && g == 0)
        lout[(size_t)(b*H + h)*S_ + qlo + fr] = lsum;

    #pragma unroll
    for (int r = 0; r < 4; r++) {
        _Float16* cp = ctx + (size_t)(b*S_ + qlo + g*4 + r)*CTXLD + h*DK;
        #pragma unroll
        for (int dt = 0; dt < DT; dt++)
            cp[dt*16 + fr] = (_Float16)(O[dt][r] * linv[r]);
    }
}

// ---------------------------------------------------------------------------
// Mega flash: all three branches in one 2048-block dispatch.
// bid < 1024: long (DK=64, BJ=128 -> half the barrier rounds; uniform-heavy,
// scheduled first). bid >= 1024: short/medium (DK=128, BJ=64), reverse-q
// order so high-tile-count blocks start early.
// ---------------------------------------------------------------------------
__global__ __launch_bounds__(256, 4) void flash_mega(
    const _Float16* __restrict__ qk_s, const _Float16* __restrict__ qk_m,
    const _Float16* __restrict__ qk_l,
    const _Float16* __restrict__ vT_s, const _Float16* __restrict__ vT_m,
    const _Float16* __restrict__ vT_l,
    _Float16* __restrict__ ctxall, float* __restrict__ lbuf)
{
    __shared__ __align__(16) _Float16 lds[18944];
    __shared__ float Lw[64];

    const int bid = blockIdx.x;
    if (bid < 1024) {
        int qblk = bid & 31, h = (bid >> 5) & 15, b = bid >> 9;
        flash_body<64, 128, true>(lds, Lw, qk_l, vT_l, ctxall + 2048, lbuf,
                                  -1, b, h, qblk, 16);
    } else {
        int r = bid - 1024;
        int qblk = 31 - (r & 31);
        int h = (r >> 5) & 7;
        int z = r >> 8;                 // 0..3 = branch*2 + batch
        int br = z >> 1, b = z & 1;
        flash_body<128, 64, false>(lds, Lw, br ? qk_m : qk_s, br ? vT_m : vT_s,
                                   ctxall + (br ? 1024 : 0), nullptr,
                                   br ? 30 : 10, b, h, qblk, 8);
    }
}

// ---------------------------------------------------------------------------
// Head-averaged long-branch attention probabilities (2 heads per barrier).
// ---------------------------------------------------------------------------
__global__ __launch_bounds__(256, 4) void attn_mean3(
    const _Float16* __restrict__ qk,
    const float* __restrict__ lbuf,
    float* __restrict__ attn)
{
    __shared__ __align__(16) _Float16 Ks[2 * 2 * 128 * 32];

    const int t = threadIdx.x, lane = t & 63, w = t >> 6;
    const int fr = lane & 15, g = lane >> 4, k8 = g * 8;
    const int j0 = blockIdx.x * 128;
    const int irow = blockIdx.y * 64 + w * 16;
    const int b = blockIdx.z;
    const float c1 = 0.125f * 1.44269504f;
    const int srow = lane >> 2, scol = (lane & 3) * 8;

    f32x4 acc[8] = {};

    for (int hp = 0; hp < 16; hp += 2) {
        __syncthreads();
        #pragma unroll
        for (int hh = 0; hh < 2; hh++)
            #pragma unroll
            for (int kk = 0; kk < 2; kk++)
                #pragma unroll
                for (int ii = 0; ii < 2; ii++)
                    GL2LDS(&qk[(size_t)(b*S_ + j0 + w*32 + ii*16 + srow)*2048
                               + 1024 + (hp+hh)*64 + kk*32 + scol],
                           &Ks[hh*8192 + kk*4096 + w*1024 + ii*512]);
        __syncthreads();

        #pragma unroll
        for (int hh = 0; hh < 2; hh++) {
            const int h = hp + hh;
            half8_t af[2];
            #pragma unroll
            for (int kk = 0; kk < 2; kk++)
                af[kk] = *(const half8_t*)
                    &qk[(size_t)(b*S_ + irow + fr)*2048 + h*64 + kk*32 + k8];

            float lg[4];
            #pragma unroll
            for (int r = 0; r < 4; r++)
                lg[r] = __log2f(lbuf[(size_t)(b*16 + h)*S_ + irow + g*4 + r]) + 4.0f;

            #pragma unroll
            for (int nt = 0; nt < 8; nt++) {
                f32x4 s = {};
                #pragma unroll
                for (int kk = 0; kk < 2; kk++) {
                    half8_t bf = *(const half8_t*)
                        &Ks[hh*8192 + kk*4096 + (nt*16 + fr)*32 + k8];
                    s = __builtin_amdgcn_mfma_f32_16x16x32_f16(af[kk], bf, s, 0, 0, 0);
                }
                #pragma unroll
                for (int r = 0; r < 4; r++)
                    acc[nt][r] += exp2f(s[r] * c1 - lg[r]);
            }
        }
    }

    #pragma unroll
    for (int r = 0; r < 4; r++) {
        float* p = attn + (size_t)(b*S_ + irow + g*4 + r)*S_ + j0;
        #pragma unroll
        for (int nt = 0; nt < 8; nt++)
            p[nt*16 + fr] = acc[nt][r];
    }
}

// ---------------------------------------------------------------------------
// Residual + LayerNorm
// ---------------------------------------------------------------------------
__global__ __launch_bounds__(256) void ln_residual(
    const float* __restrict__ pre, const float* __restrict__ x,
    const float* __restrict__ gamma, const float* __restrict__ beta,
    float* __restrict__ out)
{
    __shared__ float redS[4], redQ[4];
    const int row = blockIdx.x;
    const int t = threadIdx.x;
    size_t base = (size_t)row * D_ + t * 4;

    float4 v  = *(const float4*)(pre + base);
    float4 xv = *(const float4*)(x + base);
    v.x += xv.x; v.y += xv.y; v.z += xv.z; v.w += xv.w;

    float s = v.x + v.y + v.z + v.w;
    float q = v.x*v.x + v.y*v.y + v.z*v.z + v.w*v.w;
    #pragma unroll
    for (int m = 32; m >= 1; m >>= 1) {
        s += __shfl_xor(s, m);
        q += __shfl_xor(q, m);
    }
    int wave = t >> 6;
    if ((t & 63) == 0) { redS[wave] = s; redQ[wave] = q; }
    __syncthreads();
    s = redS[0] + redS[1] + redS[2] + redS[3];
    q = redQ[0] + redQ[1] + redQ[2] + redQ[3];

    float mean = s * (1.f / D_);
    float var  = q * (1.f / D_) - mean * mean;
    float rstd = rsqrtf(var + 1e-5f);

    float4 g  = *(const float4*)(gamma + t * 4);
    float4 be = *(const float4*)(beta + t * 4);
    float4 o;
    o.x = (v.x - mean) * rstd * g.x + be.x;
    o.y = (v.y - mean) * rstd * g.y + be.y;
    o.z = (v.z - mean) * rstd * g.z + be.z;
    o.w = (v.w - mean) * rstd * g.w + be.w;
    *(float4*)(out + base) = o;
}

// ---------------------------------------------------------------------------
extern "C" void kernel_launch(void* const* d_in, const int* in_sizes, int n_in,
                              void* d_out, int out_size, void* d_ws, size_t ws_size,
                              hipStream_t stream)
{
    (void)in_sizes; (void)n_in; (void)out_size; (void)ws_size;
    const float* x      = (const float*)d_in[0];
    const float* w_in_s = (const float*)d_in[1];
    const float* b_in_s = (const float*)d_in[2];
    const float* wo_s   = (const float*)d_in[3];
    const float* bo_s   = (const float*)d_in[4];
    const float* w_in_m = (const float*)d_in[5];
    const float* b_in_m = (const float*)d_in[6];
    const float* wo_m   = (const float*)d_in[7];
    const float* bo_m   = (const float*)d_in[8];
    const float* w_in_l = (const float*)d_in[9];
    const float* b_in_l = (const float*)d_in[10];
    const float* wo_l   = (const float*)d_in[11];
    const float* bo_l   = (const float*)d_in[12];
    const float* w_comb = (const float*)d_in[13];
    const float* b_comb = (const float*)d_in[14];
    const float* gamma  = (const float*)d_in[15];
    const float* beta   = (const float*)d_in[16];

    float* out    = (float*)d_out;                 // [B,S,D]
    float* attn_o = out + (size_t)M_ * D_;         // [B,S,S]

    // Workspace (byte offsets; total ~132.3 MB <= proven-available 134.5 MB).
    // Alias lifetimes (stream order):
    //   w_comb_h+woT_s [18,26)MB dead after weff gemm -> vT_l (qkv_all writes it after)
    //   qk_m dead after flash_mega -> pre (fused gemm output)
    char* W = (char*)d_ws;
    _Float16* w_in_s_h = (_Float16*)(W);                 //  6MB
    _Float16* w_in_m_h = (_Float16*)(W + 6291456);       //  6MB
    _Float16* w_in_l_h = (_Float16*)(W + 12582912);      //  6MB
    _Float16* w_comb_h = (_Float16*)(W + 18874368);      //  6MB (-> vT_l)
    _Float16* woT_s    = (_Float16*)(W + 25165824);      //  2MB (-> vT_l tail)
    _Float16* woT_m    = (_Float16*)(W + 27262976);      //  2MB
    _Float16* woT_l    = (_Float16*)(W + 29360128);      //  2MB
    _Float16* weff     = (_Float16*)(W + 31457280);      //  6MB
    _Float16* qk_s     = (_Float16*)(W + 37748736);      // 16MB
    _Float16* qk_m     = (_Float16*)(W + 54525952);      // 16MB (-> pre fp32)
    _Float16* qk_l     = (_Float16*)(W + 71303168);      // 16MB
    _Float16* vT_s     = (_Float16*)(W + 88080384);      //  8MB
    _Float16* vT_m     = (_Float16*)(W + 96468992);      //  8MB
    _Float16* ctxall   = (_Float16*)(W + 104857600);     // 24MB [4096][3072]
    _Float16* x_h      = (_Float16*)(W + 130023424);     //  8MB
    float*    lbuf     = (float*)   (W + 138412032);     // 256KB
    float*    beff     = (float*)   (W + 138674432);     //  4KB
    _Float16* vT_l     = w_comb_h;                       // 8MB alias (see above)
    float*    pre      = (float*)qk_m;

    dim3 blk(256);
    GemmBatch nil = { nullptr, nullptr, nullptr, nullptr, nullptr };

    // ---- casts: x, w_in x3, w_comb ----
    CastArgs ca;
    ca.s[0]=x;      ca.d[0]=x_h;      ca.nb[0]=4096;
    ca.s[1]=w_in_s; ca.d[1]=w_in_s_h; ca.nb[1]=3072;
    ca.s[2]=w_in_m; ca.d[2]=w_in_m_h; ca.nb[2]=3072;
    ca.s[3]=w_in_l; ca.d[3]=w_in_l_h; ca.nb[3]=3072;
    ca.s[4]=w_comb; ca.d[4]=w_comb_h; ca.nb[4]=3072;
    cast_all<<<dim3(16384), blk, 0, stream>>>(ca);

    // ---- transpose-cast wo_* -> woT_* ----
    transpose_cast_wo<<<dim3(16, 16, 3), blk, 0, stream>>>(
        wo_s, wo_m, wo_l, woT_s, woT_m, woT_l);

    // ---- Weff_b = Wc_b @ wo_b (fp16, no bias) ----
    GemmBatch we0 = { w_comb_h + 0,    woT_s, nullptr, weff + 0,    nullptr };
    GemmBatch we1 = { w_comb_h + 1024, woT_m, nullptr, weff + 1024, nullptr };
    GemmBatch we2 = { w_comb_h + 2048, woT_l, nullptr, weff + 2048, nullptr };
    gemm_f16<3><<<dim3(8, 8, 3), blk, 0, stream>>>(we0, we1, we2, 3072, 1024, 3072, 1024);

    // ---- beff = b_comb + Wc . bo_cat ----
    beff_kernel<<<dim3(1024), blk, 0, stream>>>(w_comb, b_comb, bo_s, bo_m, bo_l, beff);

    // ---- all three QKV projections in one dispatch (w_comb_h now dead -> vT_l) ----
    GemmBatch qs = { x_h, w_in_s_h, b_in_s, qk_s, vT_s };
    GemmBatch qm = { x_h, w_in_m_h, b_in_m, qk_m, vT_m };
    GemmBatch ql = { x_h, w_in_l_h, b_in_l, qk_l, vT_l };
    gemm_f16<2><<<dim3(M_/128, 3072/128, 3), blk, 0, stream>>>(qs, qm, ql, D_, D_, 2048, D_);

    // ---- mega flash: long + short + medium in one 2048-block dispatch ----
    flash_mega<<<dim3(2048), blk, 0, stream>>>(
        qk_s, qk_m, qk_l, vT_s, vT_m, vT_l, ctxall, lbuf);

    // ---- head-averaged probabilities ----
    attn_mean3<<<dim3(S_/128, S_/64, B_), blk, 0, stream>>>(qk_l, lbuf, attn_o);

    // ---- fused (outproj+combine): pre = ctxall @ weff^T + beff ----
    GemmBatch fb = { ctxall, weff, beff, pre, nullptr };
    gemm_f16<0><<<dim3(M_/128, D_/128, 1), blk, 0, stream>>>(fb, nil, nil, 3072, 3072, D_, 3072);

    // ---- residual LayerNorm ----
    ln_residual<<<dim3(M_), blk, 0, stream>>>(pre, x, gamma, beta, out);
}